// Round 13
// baseline (186.164 us; speedup 1.0000x reference)
//
#include <hip/hip_runtime.h>

#define DEV __device__ __forceinline__

typedef __bf16 bf16x8 __attribute__((ext_vector_type(8)));
typedef __bf16 bf16x4 __attribute__((ext_vector_type(4)));
typedef float f32x4 __attribute__((ext_vector_type(4)));
typedef unsigned u32x4 __attribute__((ext_vector_type(4)));
typedef unsigned short ushort_t;

static constexpr int EMBED = 1024;
static constexpr int NHEAD = 16;
static constexpr int HDIM  = 64;
static constexpr int S_    = 2048;
static constexpr float SCALE_L2E = 0.125f * 1.44269504088896340736f; // (1/sqrt(64))*log2(e)

DEV ushort_t f2bf(float f) {
  unsigned u = __builtin_bit_cast(unsigned, f);
  unsigned r = (u + 0x7fffu + ((u >> 16) & 1u)) >> 16;
  return (ushort_t)r;
}

// async global->LDS, 16B per lane; LDS dest is wave-uniform base + lane*16
#define GLOAD_LDS16(g, l)                                                   \
  __builtin_amdgcn_global_load_lds(                                         \
      (const __attribute__((address_space(1))) unsigned int*)(g),           \
      (__attribute__((address_space(3))) unsigned int*)(l), 16, 0, 0)

// explicit drain of global_load_lds before a publish barrier
#define DRAIN_VM() asm volatile("s_waitcnt vmcnt(0)" ::: "memory")

// ---------------------------------------------------------------------------
// fp32 -> bf16 conversion of x and the four weight matrices
// ---------------------------------------------------------------------------
__global__ __launch_bounds__(256) void convert_kernel(
    const float* __restrict__ x,
    const float* __restrict__ wq, const float* __restrict__ wk,
    const float* __restrict__ wv, const float* __restrict__ wo,
    ushort_t* __restrict__ xb, ushort_t* __restrict__ wqb,
    ushort_t* __restrict__ wkb, ushort_t* __restrict__ wvb,
    ushort_t* __restrict__ wob) {
  size_t i = ((size_t)blockIdx.x * blockDim.x + threadIdx.x) * 4;
  const float* src; ushort_t* dst; size_t off;
  if (i < 4194304u)      { src = x;  dst = xb;  off = i; }
  else if (i < 5242880u) { src = wq; dst = wqb; off = i - 4194304u; }
  else if (i < 6291456u) { src = wk; dst = wkb; off = i - 5242880u; }
  else if (i < 7340032u) { src = wv; dst = wvb; off = i - 6291456u; }
  else                   { src = wo; dst = wob; off = i - 7340032u; }
  float4 v = *(const float4*)(src + off);
  ushort4 o;
  o.x = f2bf(v.x); o.y = f2bf(v.y); o.z = f2bf(v.z); o.w = f2bf(v.w);
  *(ushort4*)(dst + off) = o;
}

// ---------------------------------------------------------------------------
// Merged QKV GEMM, 1-D grid of 768 blocks (R12-green single-buffer m97):
//   bid <256 : Q = xb @ Wq^T  -> [B,H,S,D], (acc+bias)*mask*SCALE_L2E
//   bid <512 : K = xb @ Wk^T  -> [B,H,S,D], (acc+bias)*mask
//   else     : V^T (A=Wv, B=xb) -> [B,H,D,S], acc+bias
// ---------------------------------------------------------------------------
__global__ __launch_bounds__(256) void qkv_kernel(
    const ushort_t* __restrict__ xb, const ushort_t* __restrict__ wqb,
    const ushort_t* __restrict__ wkb, const ushort_t* __restrict__ wvb,
    const float* __restrict__ bq, const float* __restrict__ bk,
    const float* __restrict__ bv, const int* __restrict__ mask,
    ushort_t* __restrict__ qo, ushort_t* __restrict__ ko,
    ushort_t* __restrict__ vto) {
  __shared__ __align__(16) unsigned char ldsA[16384];
  __shared__ __align__(16) unsigned char ldsB[16384];
  __shared__ float maskf[2][128];

  const int bid  = blockIdx.x;
  const int tid  = threadIdx.x;
  const int lane = tid & 63;
  const int w    = tid >> 6;
  const int wm   = (w >> 1) * 64;
  const int wn   = (w & 1) * 64;
  const int rl   = lane & 15;
  const int kg   = lane >> 4;

  int mode, ar0, br0;
  const ushort_t *A, *Bm;
  const float* bias;
  if (bid < 512) {
    mode = bid >> 8;                 // 0=Q, 1=K
    int t = bid & 255;
    ar0 = (t & 31) * 128;            // x rows
    br0 = (t >> 5) * 128;            // weight rows
    A = xb; Bm = mode ? wkb : wqb; bias = mode ? bk : bq;
  } else {
    mode = 2;
    int t = bid - 512;
    ar0 = (t & 7) * 128;             // weight rows
    br0 = (t >> 3) * 128;            // x rows
    A = wvb; Bm = xb; bias = bv;
  }

  if (mode < 2) {
    int hl = tid >> 7, sl = tid & 127;
    int m = ar0 + sl;
    int b = m >> 11, s = m & 2047;
    int h = (br0 >> 6) + hl;
    maskf[hl][sl] = (float)mask[((size_t)b * NHEAD + h) * S_ + s];
  }

  f32x4 acc[4][4];
#pragma unroll
  for (int i = 0; i < 4; ++i)
#pragma unroll
    for (int j = 0; j < 4; ++j) acc[i][j] = f32x4{0.f, 0.f, 0.f, 0.f};

  auto STAGE = [&](int kt) {
    const int k0 = kt * 64;
#pragma unroll
    for (int s = 0; s < 8; ++s) {
      const int basev = s * 256 + w * 64;   // wave-uniform
      const int Lb = basev & 1023;
      const int L = Lb + lane;
      const int row = L >> 3;
      const int gu = (L & 7) ^ (row & 7);
      if (s < 4) {
        GLOAD_LDS16(A + (size_t)(ar0 + row) * EMBED + k0 + gu * 8, &ldsA[Lb * 16]);
      } else {
        GLOAD_LDS16(Bm + (size_t)(br0 + row) * EMBED + k0 + gu * 8, &ldsB[Lb * 16]);
      }
    }
  };

  for (int kt = 0; kt < 16; ++kt) {
    if (kt) __syncthreads();          // all waves done reading previous tile
    STAGE(kt);
    DRAIN_VM();                       // my loads landed
    __syncthreads();                  // everyone's loads landed
#pragma unroll
    for (int kk = 0; kk < 2; ++kk) {
      bf16x8 af[4], bfr[4];
#pragma unroll
      for (int mb = 0; mb < 4; ++mb) {
        const int row = wm + mb * 16 + rl;
        const int off = (kk * 64 + kg * 16) ^ ((row & 7) << 4);
        af[mb] = *(const bf16x8*)(ldsA + row * 128 + off);
      }
#pragma unroll
      for (int nb = 0; nb < 4; ++nb) {
        const int row = wn + nb * 16 + rl;
        const int off = (kk * 64 + kg * 16) ^ ((row & 7) << 4);
        bfr[nb] = *(const bf16x8*)(ldsB + row * 128 + off);
      }
#pragma unroll
      for (int mb = 0; mb < 4; ++mb)
#pragma unroll
        for (int nb = 0; nb < 4; ++nb)
          acc[mb][nb] = __builtin_amdgcn_mfma_f32_16x16x32_bf16(
              af[mb], bfr[nb], acc[mb][nb], 0, 0, 0);
    }
  }

  // epilogue — D layout: row(A idx)=(lane>>4)*4+r, col(B idx)=lane&15
#pragma unroll
  for (int mb = 0; mb < 4; ++mb)
#pragma unroll
    for (int nb = 0; nb < 4; ++nb)
#pragma unroll
      for (int r = 0; r < 4; ++r) {
        int row_l = wm + mb * 16 + kg * 4 + r;
        int col_l = wn + nb * 16 + rl;
        float v = acc[mb][nb][r];
        if (mode < 2) {
          int m = ar0 + row_l, n = br0 + col_l;
          v = (v + bias[n]) * maskf[col_l >> 6][row_l];
          if (mode == 0) v *= SCALE_L2E;
          int b = m >> 11, s = m & 2047, h = n >> 6, d = n & 63;
          ushort_t* o = mode ? ko : qo;
          o[(((size_t)(b * NHEAD + h)) * S_ + s) * HDIM + d] = f2bf(v);
        } else {
          int n = ar0 + row_l, m = br0 + col_l;
          v += bias[n];
          int b = m >> 11, s = m & 2047, h = n >> 6, d = n & 63;
          vto[(((size_t)(b * NHEAD + h)) * HDIM + d) * S_ + s] = f2bf(v);
        }
      }
}

// ---------------------------------------------------------------------------
// O projection GEMM: out[m][n] = aob[m][:] . Wo[n][:] + bo[n]  (fp32 out)
// R12-green single-buffer m97 structure.
// ---------------------------------------------------------------------------
__global__ __launch_bounds__(256) void gemm_o_kernel(
    const ushort_t* __restrict__ A, const ushort_t* __restrict__ Bm,
    const float* __restrict__ bias, float* __restrict__ outp) {
  __shared__ __align__(16) unsigned char ldsA[16384];
  __shared__ __align__(16) unsigned char ldsB[16384];

  const int tid  = threadIdx.x;
  const int lane = tid & 63;
  const int w    = tid >> 6;
  const int ar0  = blockIdx.x * 128;
  const int br0  = blockIdx.y * 128;
  const int wm   = (w >> 1) * 64;
  const int wn   = (w & 1) * 64;
  const int rl   = lane & 15;
  const int kg   = lane >> 4;

  f32x4 acc[4][4];
#pragma unroll
  for (int i = 0; i < 4; ++i)
#pragma unroll
    for (int j = 0; j < 4; ++j) acc[i][j] = f32x4{0.f, 0.f, 0.f, 0.f};

  auto STAGE = [&](int kt) {
    const int k0 = kt * 64;
#pragma unroll
    for (int s = 0; s < 8; ++s) {
      const int basev = s * 256 + w * 64;
      const int Lb = basev & 1023;
      const int L = Lb + lane;
      const int row = L >> 3;
      const int gu = (L & 7) ^ (row & 7);
      if (s < 4) {
        GLOAD_LDS16(A + (size_t)(ar0 + row) * EMBED + k0 + gu * 8, &ldsA[Lb * 16]);
      } else {
        GLOAD_LDS16(Bm + (size_t)(br0 + row) * EMBED + k0 + gu * 8, &ldsB[Lb * 16]);
      }
    }
  };

  for (int kt = 0; kt < 16; ++kt) {
    if (kt) __syncthreads();
    STAGE(kt);
    DRAIN_VM();
    __syncthreads();
#pragma unroll
    for (int kk = 0; kk < 2; ++kk) {
      bf16x8 af[4], bfr[4];
#pragma unroll
      for (int mb = 0; mb < 4; ++mb) {
        const int row = wm + mb * 16 + rl;
        const int off = (kk * 64 + kg * 16) ^ ((row & 7) << 4);
        af[mb] = *(const bf16x8*)(ldsA + row * 128 + off);
      }
#pragma unroll
      for (int nb = 0; nb < 4; ++nb) {
        const int row = wn + nb * 16 + rl;
        const int off = (kk * 64 + kg * 16) ^ ((row & 7) << 4);
        bfr[nb] = *(const bf16x8*)(ldsB + row * 128 + off);
      }
#pragma unroll
      for (int mb = 0; mb < 4; ++mb)
#pragma unroll
        for (int nb = 0; nb < 4; ++nb)
          acc[mb][nb] = __builtin_amdgcn_mfma_f32_16x16x32_bf16(
              af[mb], bfr[nb], acc[mb][nb], 0, 0, 0);
    }
  }

#pragma unroll
  for (int mb = 0; mb < 4; ++mb)
#pragma unroll
    for (int nb = 0; nb < 4; ++nb)
#pragma unroll
      for (int r = 0; r < 4; ++r) {
        int m = ar0 + wm + mb * 16 + kg * 4 + r;
        int n = br0 + wn + nb * 16 + rl;
        outp[(size_t)m * EMBED + n] = acc[mb][nb][r] + bias[n];
      }
}

// ---------------------------------------------------------------------------
// Flash attention, swapped-QK^T, fixed-exponent softmax — BARRIER-FREE.
// K/V fragments read DIRECTLY from global into MFMA registers (no LDS
// staging): both waves of a block read the same 8KB tiles -> wave 2 hits
// L1; all qt-blocks of a head sit on one XCD -> K/V stays L2-resident.
// K software-pipelined one tile ahead in registers (kf/kn); V issued at
// body top so latency hides under QK+softmax. LDS = per-wave P buffer
// only (8 KB) -> zero __syncthreads in the kernel.
// P roundtrip + l-by-MFMA identical to R12-green.
// grid (bh=32, qt=32); 2 waves x 32 q-rows; KV tiles of 64 keys.
// ---------------------------------------------------------------------------
__global__ __launch_bounds__(128, 2) void attn_kernel(
    const ushort_t* __restrict__ qp, const ushort_t* __restrict__ kp,
    const ushort_t* __restrict__ vtp, ushort_t* __restrict__ ao) {
  __shared__ __align__(16) unsigned char ldsP[2][4096];

  const int tid  = threadIdx.x;
  const int lane = tid & 63;
  const int w    = tid >> 6;                  // 0..1
  const int bh   = blockIdx.x;
  const int q0   = blockIdx.y * 64 + w * 32;  // wave's q base
  const int rl   = lane & 15;
  const int kg   = lane >> 4;
  const int pswz = (rl & 7) << 4;

  const bf16x8 ones = __builtin_bit_cast(bf16x8,
      u32x4{0x3F803F80u, 0x3F803F80u, 0x3F803F80u, 0x3F803F80u});

  // Q fragments (B-operand): lane (rl,kg) holds Q[q=qb*16+rl][d=kk*32+kg*8..+8]
  bf16x8 qa[2][2];
#pragma unroll
  for (int qb = 0; qb < 2; ++qb)
#pragma unroll
    for (int kk = 0; kk < 2; ++kk)
      qa[qb][kk] = *(const bf16x8*)(qp + ((size_t)bh * S_ + q0 + qb * 16 + rl) * HDIM +
                                    kk * 32 + kg * 8);

  f32x4 o_acc[2][4];
  f32x4 o_l[2];
#pragma unroll
  for (int qb = 0; qb < 2; ++qb) {
#pragma unroll
    for (int nb = 0; nb < 4; ++nb) o_acc[qb][nb] = f32x4{0.f, 0.f, 0.f, 0.f};
    o_l[qb] = f32x4{0.f, 0.f, 0.f, 0.f};
  }

  unsigned char* pb = ldsP[w];
  const ushort_t* kbp = kp + (size_t)bh * S_ * HDIM;
  const ushort_t* vbp = vtp + (size_t)bh * HDIM * S_;

  // K fragments for tile 0 (A-operand): K[key=nb*16+rl][d=kk*32+kg*8..+8]
  bf16x8 kf[4][2];
#pragma unroll
  for (int nb = 0; nb < 4; ++nb)
#pragma unroll
    for (int kk = 0; kk < 2; ++kk)
      kf[nb][kk] = *(const bf16x8*)(kbp + (size_t)(nb * 16 + rl) * HDIM +
                                    kk * 32 + kg * 8);

  for (int kt = 0; kt < 32; ++kt) {
    // V fragments for this tile (B-operand): V^T[d=nb*16+rl][keys kk*32+kg*8..+8]
    // issued now, consumed after QK+softmax -> L2 latency hidden
    bf16x8 vf[4][2];
#pragma unroll
    for (int nb = 0; nb < 4; ++nb)
#pragma unroll
      for (int kk = 0; kk < 2; ++kk)
        vf[nb][kk] = *(const bf16x8*)(vbp + (size_t)(nb * 16 + rl) * S_ +
                                      kt * 64 + kk * 32 + kg * 8);
    // K prefetch for next tile
    bf16x8 kn[4][2];
    if (kt < 31) {
#pragma unroll
      for (int nb = 0; nb < 4; ++nb)
#pragma unroll
        for (int kk = 0; kk < 2; ++kk)
          kn[nb][kk] = *(const bf16x8*)(kbp + (size_t)((kt + 1) * 64 + nb * 16 + rl) * HDIM +
                                        kk * 32 + kg * 8);
    }

    // QK^T (swapped): sa[qb][nb][r] = S^T[key=nb*16+kg*4+r][q=qb*16+rl]
    f32x4 sa[2][4];
#pragma unroll
    for (int qb = 0; qb < 2; ++qb)
#pragma unroll
      for (int nb = 0; nb < 4; ++nb) sa[qb][nb] = f32x4{0.f, 0.f, 0.f, 0.f};
#pragma unroll
    for (int nb = 0; nb < 4; ++nb)
#pragma unroll
      for (int kk = 0; kk < 2; ++kk) {
        sa[0][nb] = __builtin_amdgcn_mfma_f32_16x16x32_bf16(kf[nb][kk], qa[0][kk], sa[0][nb], 0, 0, 0);
        sa[1][nb] = __builtin_amdgcn_mfma_f32_16x16x32_bf16(kf[nb][kk], qa[1][kk], sa[1][nb], 0, 0, 0);
      }

    // P = exp2(s) -> bf16, packed 8B writes into per-wave LDS P buffer:
    // row = q = qb*16+rl; byte = key*2 ^ pswz  (key = nb*16+kg*4+r)
#pragma unroll
    for (int qb = 0; qb < 2; ++qb)
#pragma unroll
      for (int nb = 0; nb < 4; ++nb) {
        bf16x4 pk4;
#pragma unroll
        for (int r = 0; r < 4; ++r)
          pk4[r] = (__bf16)__builtin_amdgcn_exp2f(sa[qb][nb][r]);
        *(bf16x4*)(pb + (qb * 16 + rl) * 128 + ((nb * 32 + kg * 8) ^ pswz)) = pk4;
      }
    asm volatile("s_waitcnt lgkmcnt(0)" ::: "memory");
    __builtin_amdgcn_sched_barrier(0);

    // read P back as MFMA-A fragments: lane (rl,kg) row q, keys kk*32+kg*8..+7
    bf16x8 pa[2][2];
#pragma unroll
    for (int qb = 0; qb < 2; ++qb)
#pragma unroll
      for (int kk = 0; kk < 2; ++kk)
        pa[qb][kk] = *(const bf16x8*)(pb + (qb * 16 + rl) * 128 +
                                      ((kk * 64 + kg * 16) ^ pswz));

    // l by MFMA: o_l[qb][r] = sum_k P[q][k]  (same bf16 P as PV -> consistent)
    o_l[0] = __builtin_amdgcn_mfma_f32_16x16x32_bf16(pa[0][0], ones, o_l[0], 0, 0, 0);
    o_l[0] = __builtin_amdgcn_mfma_f32_16x16x32_bf16(pa[0][1], ones, o_l[0], 0, 0, 0);
    o_l[1] = __builtin_amdgcn_mfma_f32_16x16x32_bf16(pa[1][0], ones, o_l[1], 0, 0, 0);
    o_l[1] = __builtin_amdgcn_mfma_f32_16x16x32_bf16(pa[1][1], ones, o_l[1], 0, 0, 0);

    // PV: O[q][d] += P[q][key] * V^T[d][key]
#pragma unroll
    for (int nb = 0; nb < 4; ++nb)
#pragma unroll
      for (int kk = 0; kk < 2; ++kk) {
        o_acc[0][nb] = __builtin_amdgcn_mfma_f32_16x16x32_bf16(pa[0][kk], vf[nb][kk], o_acc[0][nb], 0, 0, 0);
        o_acc[1][nb] = __builtin_amdgcn_mfma_f32_16x16x32_bf16(pa[1][kk], vf[nb][kk], o_acc[1][nb], 0, 0, 0);
      }

    if (kt < 31) {
#pragma unroll
      for (int nb = 0; nb < 4; ++nb)
#pragma unroll
        for (int kk = 0; kk < 2; ++kk) kf[nb][kk] = kn[nb][kk];
    }
  }

  // epilogue: O[q=qb*16+kg*4+r][d=nb*16+rl] / l[q]; o_l aligned with o_acc
  const int b = bh >> 4, h = bh & 15;
#pragma unroll
  for (int qb = 0; qb < 2; ++qb)
#pragma unroll
    for (int r = 0; r < 4; ++r) {
      float linv = 1.0f / o_l[qb][r];
      const int row = q0 + qb * 16 + kg * 4 + r;
#pragma unroll
      for (int nb = 0; nb < 4; ++nb) {
        float v = o_acc[qb][nb][r] * linv;
        ao[((size_t)b * S_ + row) * EMBED + h * HDIM + nb * 16 + rl] = f2bf(v);
      }
    }
}

// ---------------------------------------------------------------------------
extern "C" void kernel_launch(void* const* d_in, const int* in_sizes, int n_in,
                              void* d_out, int out_size, void* d_ws, size_t ws_size,
                              hipStream_t stream) {
  const float* x    = (const float*)d_in[0];
  const int*   mask = (const int*)d_in[1];
  const float* Wq   = (const float*)d_in[2];
  const float* bq   = (const float*)d_in[3];
  const float* Wk   = (const float*)d_in[4];
  const float* bk   = (const float*)d_in[5];
  const float* Wv   = (const float*)d_in[6];
  const float* bv   = (const float*)d_in[7];
  const float* Wo   = (const float*)d_in[8];
  const float* bo   = (const float*)d_in[9];

  char* ws = (char*)d_ws;
  ushort_t* xb  = (ushort_t*)(ws);
  ushort_t* wqb = (ushort_t*)(ws + 8388608);
  ushort_t* wkb = (ushort_t*)(ws + 10485760);
  ushort_t* wvb = (ushort_t*)(ws + 12582912);
  ushort_t* wob = (ushort_t*)(ws + 14680064);
  ushort_t* qb  = (ushort_t*)(ws + 16777216);
  ushort_t* kb  = (ushort_t*)(ws + 25165824);
  ushort_t* vtb = (ushort_t*)(ws + 33554432);
  ushort_t* aob = (ushort_t*)(ws + 41943040);

  hipLaunchKernelGGL(convert_kernel, dim3(8192), dim3(256), 0, stream,
                     x, Wq, Wk, Wv, Wo, xb, wqb, wkb, wvb, wob);
  hipLaunchKernelGGL(qkv_kernel, dim3(768), dim3(256), 0, stream,
                     xb, wqb, wkb, wvb, bq, bk, bv, mask, qb, kb, vtb);
  hipLaunchKernelGGL(attn_kernel, dim3(32, 32), dim3(128), 0, stream,
                     qb, kb, vtb, aob);
  hipLaunchKernelGGL(gemm_o_kernel, dim3(32, 8), dim3(256), 0, stream,
                     aob, wob, bo, (float*)d_out);
}

// Round 15
// 123.943 us; speedup vs baseline: 1.5020x; 1.5020x over previous
//
#include <hip/hip_runtime.h>

#define DEV __device__ __forceinline__

typedef __bf16 bf16x8 __attribute__((ext_vector_type(8)));
typedef __bf16 bf16x4 __attribute__((ext_vector_type(4)));
typedef float f32x4 __attribute__((ext_vector_type(4)));
typedef unsigned u32x4 __attribute__((ext_vector_type(4)));
typedef unsigned short ushort_t;

static constexpr int EMBED = 1024;
static constexpr int NHEAD = 16;
static constexpr int HDIM  = 64;
static constexpr int S_    = 2048;
static constexpr float SCALE_L2E = 0.125f * 1.44269504088896340736f; // (1/sqrt(64))*log2(e)

DEV ushort_t f2bf(float f) {
  unsigned u = __builtin_bit_cast(unsigned, f);
  unsigned r = (u + 0x7fffu + ((u >> 16) & 1u)) >> 16;
  return (ushort_t)r;
}

// async global->LDS, 16B per lane; LDS dest is wave-uniform base + lane*16
#define GLOAD_LDS16(g, l)                                                   \
  __builtin_amdgcn_global_load_lds(                                         \
      (const __attribute__((address_space(1))) unsigned int*)(g),           \
      (__attribute__((address_space(3))) unsigned int*)(l), 16, 0, 0)

// explicit drain of global_load_lds before a publish barrier
#define DRAIN_VM() asm volatile("s_waitcnt vmcnt(0)" ::: "memory")

// ---------------------------------------------------------------------------
// fp32 -> bf16 conversion of x and the four weight matrices
// ---------------------------------------------------------------------------
__global__ __launch_bounds__(256) void convert_kernel(
    const float* __restrict__ x,
    const float* __restrict__ wq, const float* __restrict__ wk,
    const float* __restrict__ wv, const float* __restrict__ wo,
    ushort_t* __restrict__ xb, ushort_t* __restrict__ wqb,
    ushort_t* __restrict__ wkb, ushort_t* __restrict__ wvb,
    ushort_t* __restrict__ wob) {
  size_t i = ((size_t)blockIdx.x * blockDim.x + threadIdx.x) * 4;
  const float* src; ushort_t* dst; size_t off;
  if (i < 4194304u)      { src = x;  dst = xb;  off = i; }
  else if (i < 5242880u) { src = wq; dst = wqb; off = i - 4194304u; }
  else if (i < 6291456u) { src = wk; dst = wkb; off = i - 5242880u; }
  else if (i < 7340032u) { src = wv; dst = wvb; off = i - 6291456u; }
  else                   { src = wo; dst = wob; off = i - 7340032u; }
  float4 v = *(const float4*)(src + off);
  ushort4 o;
  o.x = f2bf(v.x); o.y = f2bf(v.y); o.z = f2bf(v.z); o.w = f2bf(v.w);
  *(ushort4*)(dst + off) = o;
}

// ---------------------------------------------------------------------------
// Merged QKV GEMM, 1-D grid of 768 blocks (R12-green single-buffer m97):
//   bid <256 : Q = xb @ Wq^T  -> [B,H,S,D], (acc+bias)*mask*SCALE_L2E
//   bid <512 : K = xb @ Wk^T  -> [B,H,S,D], (acc+bias)*mask
//   else     : V^T (A=Wv, B=xb) -> [B,H,D,S], acc+bias
// ---------------------------------------------------------------------------
__global__ __launch_bounds__(256) void qkv_kernel(
    const ushort_t* __restrict__ xb, const ushort_t* __restrict__ wqb,
    const ushort_t* __restrict__ wkb, const ushort_t* __restrict__ wvb,
    const float* __restrict__ bq, const float* __restrict__ bk,
    const float* __restrict__ bv, const int* __restrict__ mask,
    ushort_t* __restrict__ qo, ushort_t* __restrict__ ko,
    ushort_t* __restrict__ vto) {
  __shared__ __align__(16) unsigned char ldsA[16384];
  __shared__ __align__(16) unsigned char ldsB[16384];
  __shared__ float maskf[2][128];

  const int bid  = blockIdx.x;
  const int tid  = threadIdx.x;
  const int lane = tid & 63;
  const int w    = tid >> 6;
  const int wm   = (w >> 1) * 64;
  const int wn   = (w & 1) * 64;
  const int rl   = lane & 15;
  const int kg   = lane >> 4;

  int mode, ar0, br0;
  const ushort_t *A, *Bm;
  const float* bias;
  if (bid < 512) {
    mode = bid >> 8;                 // 0=Q, 1=K
    int t = bid & 255;
    ar0 = (t & 31) * 128;            // x rows
    br0 = (t >> 5) * 128;            // weight rows
    A = xb; Bm = mode ? wkb : wqb; bias = mode ? bk : bq;
  } else {
    mode = 2;
    int t = bid - 512;
    ar0 = (t & 7) * 128;             // weight rows
    br0 = (t >> 3) * 128;            // x rows
    A = wvb; Bm = xb; bias = bv;
  }

  if (mode < 2) {
    int hl = tid >> 7, sl = tid & 127;
    int m = ar0 + sl;
    int b = m >> 11, s = m & 2047;
    int h = (br0 >> 6) + hl;
    maskf[hl][sl] = (float)mask[((size_t)b * NHEAD + h) * S_ + s];
  }

  f32x4 acc[4][4];
#pragma unroll
  for (int i = 0; i < 4; ++i)
#pragma unroll
    for (int j = 0; j < 4; ++j) acc[i][j] = f32x4{0.f, 0.f, 0.f, 0.f};

  auto STAGE = [&](int kt) {
    const int k0 = kt * 64;
#pragma unroll
    for (int s = 0; s < 8; ++s) {
      const int basev = s * 256 + w * 64;   // wave-uniform
      const int Lb = basev & 1023;
      const int L = Lb + lane;
      const int row = L >> 3;
      const int gu = (L & 7) ^ (row & 7);
      if (s < 4) {
        GLOAD_LDS16(A + (size_t)(ar0 + row) * EMBED + k0 + gu * 8, &ldsA[Lb * 16]);
      } else {
        GLOAD_LDS16(Bm + (size_t)(br0 + row) * EMBED + k0 + gu * 8, &ldsB[Lb * 16]);
      }
    }
  };

  for (int kt = 0; kt < 16; ++kt) {
    if (kt) __syncthreads();          // all waves done reading previous tile
    STAGE(kt);
    DRAIN_VM();                       // my loads landed
    __syncthreads();                  // everyone's loads landed
#pragma unroll
    for (int kk = 0; kk < 2; ++kk) {
      bf16x8 af[4], bfr[4];
#pragma unroll
      for (int mb = 0; mb < 4; ++mb) {
        const int row = wm + mb * 16 + rl;
        const int off = (kk * 64 + kg * 16) ^ ((row & 7) << 4);
        af[mb] = *(const bf16x8*)(ldsA + row * 128 + off);
      }
#pragma unroll
      for (int nb = 0; nb < 4; ++nb) {
        const int row = wn + nb * 16 + rl;
        const int off = (kk * 64 + kg * 16) ^ ((row & 7) << 4);
        bfr[nb] = *(const bf16x8*)(ldsB + row * 128 + off);
      }
#pragma unroll
      for (int mb = 0; mb < 4; ++mb)
#pragma unroll
        for (int nb = 0; nb < 4; ++nb)
          acc[mb][nb] = __builtin_amdgcn_mfma_f32_16x16x32_bf16(
              af[mb], bfr[nb], acc[mb][nb], 0, 0, 0);
    }
  }

  // epilogue — D layout: row(A idx)=(lane>>4)*4+r, col(B idx)=lane&15
#pragma unroll
  for (int mb = 0; mb < 4; ++mb)
#pragma unroll
    for (int nb = 0; nb < 4; ++nb)
#pragma unroll
      for (int r = 0; r < 4; ++r) {
        int row_l = wm + mb * 16 + kg * 4 + r;
        int col_l = wn + nb * 16 + rl;
        float v = acc[mb][nb][r];
        if (mode < 2) {
          int m = ar0 + row_l, n = br0 + col_l;
          v = (v + bias[n]) * maskf[col_l >> 6][row_l];
          if (mode == 0) v *= SCALE_L2E;
          int b = m >> 11, s = m & 2047, h = n >> 6, d = n & 63;
          ushort_t* o = mode ? ko : qo;
          o[(((size_t)(b * NHEAD + h)) * S_ + s) * HDIM + d] = f2bf(v);
        } else {
          int n = ar0 + row_l, m = br0 + col_l;
          v += bias[n];
          int b = m >> 11, s = m & 2047, h = n >> 6, d = n & 63;
          vto[(((size_t)(b * NHEAD + h)) * HDIM + d) * S_ + s] = f2bf(v);
        }
      }
}

// ---------------------------------------------------------------------------
// O projection GEMM: out[m][n] = aob[m][:] . Wo[n][:] + bo[n]  (fp32 out)
// R12-green single-buffer m97 structure.
// ---------------------------------------------------------------------------
__global__ __launch_bounds__(256) void gemm_o_kernel(
    const ushort_t* __restrict__ A, const ushort_t* __restrict__ Bm,
    const float* __restrict__ bias, float* __restrict__ outp) {
  __shared__ __align__(16) unsigned char ldsA[16384];
  __shared__ __align__(16) unsigned char ldsB[16384];

  const int tid  = threadIdx.x;
  const int lane = tid & 63;
  const int w    = tid >> 6;
  const int ar0  = blockIdx.x * 128;
  const int br0  = blockIdx.y * 128;
  const int wm   = (w >> 1) * 64;
  const int wn   = (w & 1) * 64;
  const int rl   = lane & 15;
  const int kg   = lane >> 4;

  f32x4 acc[4][4];
#pragma unroll
  for (int i = 0; i < 4; ++i)
#pragma unroll
    for (int j = 0; j < 4; ++j) acc[i][j] = f32x4{0.f, 0.f, 0.f, 0.f};

  auto STAGE = [&](int kt) {
    const int k0 = kt * 64;
#pragma unroll
    for (int s = 0; s < 8; ++s) {
      const int basev = s * 256 + w * 64;
      const int Lb = basev & 1023;
      const int L = Lb + lane;
      const int row = L >> 3;
      const int gu = (L & 7) ^ (row & 7);
      if (s < 4) {
        GLOAD_LDS16(A + (size_t)(ar0 + row) * EMBED + k0 + gu * 8, &ldsA[Lb * 16]);
      } else {
        GLOAD_LDS16(Bm + (size_t)(br0 + row) * EMBED + k0 + gu * 8, &ldsB[Lb * 16]);
      }
    }
  };

  for (int kt = 0; kt < 16; ++kt) {
    if (kt) __syncthreads();
    STAGE(kt);
    DRAIN_VM();
    __syncthreads();
#pragma unroll
    for (int kk = 0; kk < 2; ++kk) {
      bf16x8 af[4], bfr[4];
#pragma unroll
      for (int mb = 0; mb < 4; ++mb) {
        const int row = wm + mb * 16 + rl;
        const int off = (kk * 64 + kg * 16) ^ ((row & 7) << 4);
        af[mb] = *(const bf16x8*)(ldsA + row * 128 + off);
      }
#pragma unroll
      for (int nb = 0; nb < 4; ++nb) {
        const int row = wn + nb * 16 + rl;
        const int off = (kk * 64 + kg * 16) ^ ((row & 7) << 4);
        bfr[nb] = *(const bf16x8*)(ldsB + row * 128 + off);
      }
#pragma unroll
      for (int mb = 0; mb < 4; ++mb)
#pragma unroll
        for (int nb = 0; nb < 4; ++nb)
          acc[mb][nb] = __builtin_amdgcn_mfma_f32_16x16x32_bf16(
              af[mb], bfr[nb], acc[mb][nb], 0, 0, 0);
    }
  }

#pragma unroll
  for (int mb = 0; mb < 4; ++mb)
#pragma unroll
    for (int nb = 0; nb < 4; ++nb)
#pragma unroll
      for (int r = 0; r < 4; ++r) {
        int m = ar0 + wm + mb * 16 + kg * 4 + r;
        int n = br0 + wn + nb * 16 + rl;
        outp[(size_t)m * EMBED + n] = acc[mb][nb][r] + bias[n];
      }
}

// ---------------------------------------------------------------------------
// Flash attention, swapped-QK^T, fixed-exponent softmax (R12-green inner
// loop) — L2-TRAFFIC-OPTIMIZED:
//  * 4 waves x 32 q = 128 q/block -> K/V staged once feeds 4 waves
//    (L2 traffic halved vs R12: 2048->512 blocks x 512KB/block)
//  * grid (qt=16, bh=32): consecutive blocks share a head -> each XCD's
//    resident blocks span ~4 heads = 2MB < 4MB L2 -> K/V L2-resident
// P roundtrip + l-by-MFMA per wave identical to R12-green.
// LDS: K dbuf 16KB + V dbuf 16KB + P 4x4KB = 48KB -> 2 blocks/CU resident.
// ---------------------------------------------------------------------------
__global__ __launch_bounds__(256) void attn_kernel(
    const ushort_t* __restrict__ qp, const ushort_t* __restrict__ kp,
    const ushort_t* __restrict__ vtp, ushort_t* __restrict__ ao) {
  __shared__ __align__(16) unsigned char ldsK[2][8192];
  __shared__ __align__(16) unsigned char ldsV[2][8192];
  __shared__ __align__(16) unsigned char ldsP[4][4096];

  const int tid  = threadIdx.x;
  const int lane = tid & 63;
  const int w    = tid >> 6;                  // 0..3
  const int bh   = blockIdx.y;
  const int q0   = blockIdx.x * 128 + w * 32; // wave's q base
  const int rl   = lane & 15;
  const int kg   = lane >> 4;
  const int pswz = (rl & 7) << 4;

  const bf16x8 ones = __builtin_bit_cast(bf16x8,
      u32x4{0x3F803F80u, 0x3F803F80u, 0x3F803F80u, 0x3F803F80u});

  // Q fragments (B-operand): lane (rl,kg) holds Q[q=qb*16+rl][d=kk*32+kg*8..+8]
  bf16x8 qa[2][2];
#pragma unroll
  for (int qb = 0; qb < 2; ++qb)
#pragma unroll
    for (int kk = 0; kk < 2; ++kk)
      qa[qb][kk] = *(const bf16x8*)(qp + ((size_t)bh * S_ + q0 + qb * 16 + rl) * HDIM +
                                    kk * 32 + kg * 8);

  f32x4 o_acc[2][4];
  f32x4 o_l[2];
#pragma unroll
  for (int qb = 0; qb < 2; ++qb) {
#pragma unroll
    for (int nb = 0; nb < 4; ++nb) o_acc[qb][nb] = f32x4{0.f, 0.f, 0.f, 0.f};
    o_l[qb] = f32x4{0.f, 0.f, 0.f, 0.f};
  }

  unsigned char* pb = ldsP[w];

  // stage KV tile kt: 512 16B-units K + 512 V, 256 threads x 4 insts
  auto STAGE = [&](int kt, int bsel) {
#pragma unroll
    for (int s = 0; s < 4; ++s) {
      const int Lb = (s & 1) * 256 + w * 64;  // wave-uniform
      const int L = Lb + lane;
      const int row = L >> 3;
      const int gu = (L & 7) ^ (row & 7);
      if (s < 2) {
        GLOAD_LDS16(kp + ((size_t)bh * S_ + (size_t)kt * 64 + row) * HDIM + gu * 8,
                    &ldsK[bsel][Lb * 16]);
      } else {
        GLOAD_LDS16(vtp + ((size_t)bh * HDIM + row) * S_ + (size_t)kt * 64 + gu * 8,
                    &ldsV[bsel][Lb * 16]);
      }
    }
  };

  STAGE(0, 0);
  DRAIN_VM();
  __syncthreads();
  int cb = 0;
  for (int kt = 0; kt < 32; ++kt) {
    if (kt < 31) STAGE(kt + 1, cb ^ 1);

    // QK^T (swapped): sa[qb][nb][r] = S^T[key=nb*16+kg*4+r][q=qb*16+rl]
    f32x4 sa[2][4];
#pragma unroll
    for (int qb = 0; qb < 2; ++qb)
#pragma unroll
      for (int nb = 0; nb < 4; ++nb) sa[qb][nb] = f32x4{0.f, 0.f, 0.f, 0.f};
#pragma unroll
    for (int nb = 0; nb < 4; ++nb) {
      const int row = nb * 16 + rl;
#pragma unroll
      for (int kk = 0; kk < 2; ++kk) {
        bf16x8 kf = *(const bf16x8*)(ldsK[cb] + row * 128 +
                                     ((kk * 64 + kg * 16) ^ ((row & 7) << 4)));
        sa[0][nb] = __builtin_amdgcn_mfma_f32_16x16x32_bf16(kf, qa[0][kk], sa[0][nb], 0, 0, 0);
        sa[1][nb] = __builtin_amdgcn_mfma_f32_16x16x32_bf16(kf, qa[1][kk], sa[1][nb], 0, 0, 0);
      }
    }

    // P = exp2(s) -> bf16, packed 8B writes into per-wave LDS P buffer:
    // row = q = qb*16+rl; byte = key*2 ^ pswz  (key = nb*16+kg*4+r)
#pragma unroll
    for (int qb = 0; qb < 2; ++qb)
#pragma unroll
      for (int nb = 0; nb < 4; ++nb) {
        bf16x4 pk4;
#pragma unroll
        for (int r = 0; r < 4; ++r)
          pk4[r] = (__bf16)__builtin_amdgcn_exp2f(sa[qb][nb][r]);
        *(bf16x4*)(pb + (qb * 16 + rl) * 128 + ((nb * 32 + kg * 8) ^ pswz)) = pk4;
      }
    asm volatile("s_waitcnt lgkmcnt(0)" ::: "memory");
    __builtin_amdgcn_sched_barrier(0);

    // read P back as MFMA-A fragments: lane (rl,kg) row q, keys kk*32+kg*8..+7
    bf16x8 pa[2][2];
#pragma unroll
    for (int qb = 0; qb < 2; ++qb)
#pragma unroll
      for (int kk = 0; kk < 2; ++kk)
        pa[qb][kk] = *(const bf16x8*)(pb + (qb * 16 + rl) * 128 +
                                      ((kk * 64 + kg * 16) ^ pswz));

    // l by MFMA: o_l[qb][r] = sum_k P[q][k]  (same bf16 P as PV -> consistent)
    o_l[0] = __builtin_amdgcn_mfma_f32_16x16x32_bf16(pa[0][0], ones, o_l[0], 0, 0, 0);
    o_l[0] = __builtin_amdgcn_mfma_f32_16x16x32_bf16(pa[0][1], ones, o_l[0], 0, 0, 0);
    o_l[1] = __builtin_amdgcn_mfma_f32_16x16x32_bf16(pa[1][0], ones, o_l[1], 0, 0, 0);
    o_l[1] = __builtin_amdgcn_mfma_f32_16x16x32_bf16(pa[1][1], ones, o_l[1], 0, 0, 0);

    // PV: O[q][d] += P[q][key] * V^T[d][key]
#pragma unroll
    for (int nb = 0; nb < 4; ++nb) {
      const int row = nb * 16 + rl;
#pragma unroll
      for (int kk = 0; kk < 2; ++kk) {
        bf16x8 vb = *(const bf16x8*)(ldsV[cb] + row * 128 +
                                     ((kk * 64 + kg * 16) ^ ((row & 7) << 4)));
        o_acc[0][nb] = __builtin_amdgcn_mfma_f32_16x16x32_bf16(pa[0][kk], vb, o_acc[0][nb], 0, 0, 0);
        o_acc[1][nb] = __builtin_amdgcn_mfma_f32_16x16x32_bf16(pa[1][kk], vb, o_acc[1][nb], 0, 0, 0);
      }
    }

    DRAIN_VM();                       // prefetch landed before publish barrier
    __syncthreads();
    cb ^= 1;
  }

  // epilogue: O[q=qb*16+kg*4+r][d=nb*16+rl] / l[q]; o_l aligned with o_acc
  const int b = bh >> 4, h = bh & 15;
#pragma unroll
  for (int qb = 0; qb < 2; ++qb)
#pragma unroll
    for (int r = 0; r < 4; ++r) {
      float linv = 1.0f / o_l[qb][r];
      const int row = q0 + qb * 16 + kg * 4 + r;
#pragma unroll
      for (int nb = 0; nb < 4; ++nb) {
        float v = o_acc[qb][nb][r] * linv;
        ao[((size_t)b * S_ + row) * EMBED + h * HDIM + nb * 16 + rl] = f2bf(v);
      }
    }
}

// ---------------------------------------------------------------------------
extern "C" void kernel_launch(void* const* d_in, const int* in_sizes, int n_in,
                              void* d_out, int out_size, void* d_ws, size_t ws_size,
                              hipStream_t stream) {
  const float* x    = (const float*)d_in[0];
  const int*   mask = (const int*)d_in[1];
  const float* Wq   = (const float*)d_in[2];
  const float* bq   = (const float*)d_in[3];
  const float* Wk   = (const float*)d_in[4];
  const float* bk   = (const float*)d_in[5];
  const float* Wv   = (const float*)d_in[6];
  const float* bv   = (const float*)d_in[7];
  const float* Wo   = (const float*)d_in[8];
  const float* bo   = (const float*)d_in[9];

  char* ws = (char*)d_ws;
  ushort_t* xb  = (ushort_t*)(ws);
  ushort_t* wqb = (ushort_t*)(ws + 8388608);
  ushort_t* wkb = (ushort_t*)(ws + 10485760);
  ushort_t* wvb = (ushort_t*)(ws + 12582912);
  ushort_t* wob = (ushort_t*)(ws + 14680064);
  ushort_t* qb  = (ushort_t*)(ws + 16777216);
  ushort_t* kb  = (ushort_t*)(ws + 25165824);
  ushort_t* vtb = (ushort_t*)(ws + 33554432);
  ushort_t* aob = (ushort_t*)(ws + 41943040);

  hipLaunchKernelGGL(convert_kernel, dim3(8192), dim3(256), 0, stream,
                     x, Wq, Wk, Wv, Wo, xb, wqb, wkb, wvb, wob);
  hipLaunchKernelGGL(qkv_kernel, dim3(768), dim3(256), 0, stream,
                     xb, wqb, wkb, wvb, bq, bk, bv, mask, qb, kb, vtb);
  hipLaunchKernelGGL(attn_kernel, dim3(16, 32), dim3(256), 0, stream,
                     qb, kb, vtb, aob);
  hipLaunchKernelGGL(gemm_o_kernel, dim3(32, 8), dim3(256), 0, stream,
                     aob, wob, bo, (float*)d_out);
}

// Round 17
// 119.141 us; speedup vs baseline: 1.5626x; 1.0403x over previous
//
#include <hip/hip_runtime.h>

#define DEV __device__ __forceinline__

typedef __bf16 bf16x8 __attribute__((ext_vector_type(8)));
typedef __bf16 bf16x4 __attribute__((ext_vector_type(4)));
typedef float f32x4 __attribute__((ext_vector_type(4)));
typedef unsigned u32x4 __attribute__((ext_vector_type(4)));
typedef unsigned short ushort_t;

static constexpr int EMBED = 1024;
static constexpr int NHEAD = 16;
static constexpr int HDIM  = 64;
static constexpr int S_    = 2048;
static constexpr float SCALE_L2E = 0.125f * 1.44269504088896340736f; // (1/sqrt(64))*log2(e)

DEV ushort_t f2bf(float f) {
  unsigned u = __builtin_bit_cast(unsigned, f);
  unsigned r = (u + 0x7fffu + ((u >> 16) & 1u)) >> 16;
  return (ushort_t)r;
}

// async global->LDS, 16B per lane; LDS dest is wave-uniform base + lane*16
#define GLOAD_LDS16(g, l)                                                   \
  __builtin_amdgcn_global_load_lds(                                         \
      (const __attribute__((address_space(1))) unsigned int*)(g),           \
      (__attribute__((address_space(3))) unsigned int*)(l), 16, 0, 0)

// explicit drain of global_load_lds before a publish barrier
#define DRAIN_VM() asm volatile("s_waitcnt vmcnt(0)" ::: "memory")

// ---------------------------------------------------------------------------
// fp32 -> bf16 conversion of x and the four weight matrices
// ---------------------------------------------------------------------------
__global__ __launch_bounds__(256) void convert_kernel(
    const float* __restrict__ x,
    const float* __restrict__ wq, const float* __restrict__ wk,
    const float* __restrict__ wv, const float* __restrict__ wo,
    ushort_t* __restrict__ xb, ushort_t* __restrict__ wqb,
    ushort_t* __restrict__ wkb, ushort_t* __restrict__ wvb,
    ushort_t* __restrict__ wob) {
  size_t i = ((size_t)blockIdx.x * blockDim.x + threadIdx.x) * 4;
  const float* src; ushort_t* dst; size_t off;
  if (i < 4194304u)      { src = x;  dst = xb;  off = i; }
  else if (i < 5242880u) { src = wq; dst = wqb; off = i - 4194304u; }
  else if (i < 6291456u) { src = wk; dst = wkb; off = i - 5242880u; }
  else if (i < 7340032u) { src = wv; dst = wvb; off = i - 6291456u; }
  else                   { src = wo; dst = wob; off = i - 7340032u; }
  float4 v = *(const float4*)(src + off);
  ushort4 o;
  o.x = f2bf(v.x); o.y = f2bf(v.y); o.z = f2bf(v.z); o.w = f2bf(v.w);
  *(ushort4*)(dst + off) = o;
}

// ---------------------------------------------------------------------------
// Merged QKV GEMM, 1-D grid of 768 blocks (R12-green single-buffer m97):
//   bid <256 : Q = xb @ Wq^T  -> [B,H,S,D], (acc+bias)*mask*SCALE_L2E
//   bid <512 : K = xb @ Wk^T  -> [B,H,S,D], (acc+bias)*mask
//   else     : V^T (A=Wv, B=xb) -> [B,H,D,S], acc+bias
// ---------------------------------------------------------------------------
__global__ __launch_bounds__(256) void qkv_kernel(
    const ushort_t* __restrict__ xb, const ushort_t* __restrict__ wqb,
    const ushort_t* __restrict__ wkb, const ushort_t* __restrict__ wvb,
    const float* __restrict__ bq, const float* __restrict__ bk,
    const float* __restrict__ bv, const int* __restrict__ mask,
    ushort_t* __restrict__ qo, ushort_t* __restrict__ ko,
    ushort_t* __restrict__ vto) {
  __shared__ __align__(16) unsigned char ldsA[16384];
  __shared__ __align__(16) unsigned char ldsB[16384];
  __shared__ float maskf[2][128];

  const int bid  = blockIdx.x;
  const int tid  = threadIdx.x;
  const int lane = tid & 63;
  const int w    = tid >> 6;
  const int wm   = (w >> 1) * 64;
  const int wn   = (w & 1) * 64;
  const int rl   = lane & 15;
  const int kg   = lane >> 4;

  int mode, ar0, br0;
  const ushort_t *A, *Bm;
  const float* bias;
  if (bid < 512) {
    mode = bid >> 8;                 // 0=Q, 1=K
    int t = bid & 255;
    ar0 = (t & 31) * 128;            // x rows
    br0 = (t >> 5) * 128;            // weight rows
    A = xb; Bm = mode ? wkb : wqb; bias = mode ? bk : bq;
  } else {
    mode = 2;
    int t = bid - 512;
    ar0 = (t & 7) * 128;             // weight rows
    br0 = (t >> 3) * 128;            // x rows
    A = wvb; Bm = xb; bias = bv;
  }

  if (mode < 2) {
    int hl = tid >> 7, sl = tid & 127;
    int m = ar0 + sl;
    int b = m >> 11, s = m & 2047;
    int h = (br0 >> 6) + hl;
    maskf[hl][sl] = (float)mask[((size_t)b * NHEAD + h) * S_ + s];
  }

  f32x4 acc[4][4];
#pragma unroll
  for (int i = 0; i < 4; ++i)
#pragma unroll
    for (int j = 0; j < 4; ++j) acc[i][j] = f32x4{0.f, 0.f, 0.f, 0.f};

  auto STAGE = [&](int kt) {
    const int k0 = kt * 64;
#pragma unroll
    for (int s = 0; s < 8; ++s) {
      const int basev = s * 256 + w * 64;   // wave-uniform
      const int Lb = basev & 1023;
      const int L = Lb + lane;
      const int row = L >> 3;
      const int gu = (L & 7) ^ (row & 7);
      if (s < 4) {
        GLOAD_LDS16(A + (size_t)(ar0 + row) * EMBED + k0 + gu * 8, &ldsA[Lb * 16]);
      } else {
        GLOAD_LDS16(Bm + (size_t)(br0 + row) * EMBED + k0 + gu * 8, &ldsB[Lb * 16]);
      }
    }
  };

  for (int kt = 0; kt < 16; ++kt) {
    if (kt) __syncthreads();          // all waves done reading previous tile
    STAGE(kt);
    DRAIN_VM();                       // my loads landed
    __syncthreads();                  // everyone's loads landed
#pragma unroll
    for (int kk = 0; kk < 2; ++kk) {
      bf16x8 af[4], bfr[4];
#pragma unroll
      for (int mb = 0; mb < 4; ++mb) {
        const int row = wm + mb * 16 + rl;
        const int off = (kk * 64 + kg * 16) ^ ((row & 7) << 4);
        af[mb] = *(const bf16x8*)(ldsA + row * 128 + off);
      }
#pragma unroll
      for (int nb = 0; nb < 4; ++nb) {
        const int row = wn + nb * 16 + rl;
        const int off = (kk * 64 + kg * 16) ^ ((row & 7) << 4);
        bfr[nb] = *(const bf16x8*)(ldsB + row * 128 + off);
      }
#pragma unroll
      for (int mb = 0; mb < 4; ++mb)
#pragma unroll
        for (int nb = 0; nb < 4; ++nb)
          acc[mb][nb] = __builtin_amdgcn_mfma_f32_16x16x32_bf16(
              af[mb], bfr[nb], acc[mb][nb], 0, 0, 0);
    }
  }

  // epilogue — D layout: row(A idx)=(lane>>4)*4+r, col(B idx)=lane&15
#pragma unroll
  for (int mb = 0; mb < 4; ++mb)
#pragma unroll
    for (int nb = 0; nb < 4; ++nb)
#pragma unroll
      for (int r = 0; r < 4; ++r) {
        int row_l = wm + mb * 16 + kg * 4 + r;
        int col_l = wn + nb * 16 + rl;
        float v = acc[mb][nb][r];
        if (mode < 2) {
          int m = ar0 + row_l, n = br0 + col_l;
          v = (v + bias[n]) * maskf[col_l >> 6][row_l];
          if (mode == 0) v *= SCALE_L2E;
          int b = m >> 11, s = m & 2047, h = n >> 6, d = n & 63;
          ushort_t* o = mode ? ko : qo;
          o[(((size_t)(b * NHEAD + h)) * S_ + s) * HDIM + d] = f2bf(v);
        } else {
          int n = ar0 + row_l, m = br0 + col_l;
          v += bias[n];
          int b = m >> 11, s = m & 2047, h = n >> 6, d = n & 63;
          vto[(((size_t)(b * NHEAD + h)) * HDIM + d) * S_ + s] = f2bf(v);
        }
      }
}

// ---------------------------------------------------------------------------
// O projection GEMM: out[m][n] = aob[m][:] . Wo[n][:] + bo[n]  (fp32 out)
// R12-green single-buffer m97 structure.
// ---------------------------------------------------------------------------
__global__ __launch_bounds__(256) void gemm_o_kernel(
    const ushort_t* __restrict__ A, const ushort_t* __restrict__ Bm,
    const float* __restrict__ bias, float* __restrict__ outp) {
  __shared__ __align__(16) unsigned char ldsA[16384];
  __shared__ __align__(16) unsigned char ldsB[16384];

  const int tid  = threadIdx.x;
  const int lane = tid & 63;
  const int w    = tid >> 6;
  const int ar0  = blockIdx.x * 128;
  const int br0  = blockIdx.y * 128;
  const int wm   = (w >> 1) * 64;
  const int wn   = (w & 1) * 64;
  const int rl   = lane & 15;
  const int kg   = lane >> 4;

  f32x4 acc[4][4];
#pragma unroll
  for (int i = 0; i < 4; ++i)
#pragma unroll
    for (int j = 0; j < 4; ++j) acc[i][j] = f32x4{0.f, 0.f, 0.f, 0.f};

  auto STAGE = [&](int kt) {
    const int k0 = kt * 64;
#pragma unroll
    for (int s = 0; s < 8; ++s) {
      const int basev = s * 256 + w * 64;
      const int Lb = basev & 1023;
      const int L = Lb + lane;
      const int row = L >> 3;
      const int gu = (L & 7) ^ (row & 7);
      if (s < 4) {
        GLOAD_LDS16(A + (size_t)(ar0 + row) * EMBED + k0 + gu * 8, &ldsA[Lb * 16]);
      } else {
        GLOAD_LDS16(Bm + (size_t)(br0 + row) * EMBED + k0 + gu * 8, &ldsB[Lb * 16]);
      }
    }
  };

  for (int kt = 0; kt < 16; ++kt) {
    if (kt) __syncthreads();
    STAGE(kt);
    DRAIN_VM();
    __syncthreads();
#pragma unroll
    for (int kk = 0; kk < 2; ++kk) {
      bf16x8 af[4], bfr[4];
#pragma unroll
      for (int mb = 0; mb < 4; ++mb) {
        const int row = wm + mb * 16 + rl;
        const int off = (kk * 64 + kg * 16) ^ ((row & 7) << 4);
        af[mb] = *(const bf16x8*)(ldsA + row * 128 + off);
      }
#pragma unroll
      for (int nb = 0; nb < 4; ++nb) {
        const int row = wn + nb * 16 + rl;
        const int off = (kk * 64 + kg * 16) ^ ((row & 7) << 4);
        bfr[nb] = *(const bf16x8*)(ldsB + row * 128 + off);
      }
#pragma unroll
      for (int mb = 0; mb < 4; ++mb)
#pragma unroll
        for (int nb = 0; nb < 4; ++nb)
          acc[mb][nb] = __builtin_amdgcn_mfma_f32_16x16x32_bf16(
              af[mb], bfr[nb], acc[mb][nb], 0, 0, 0);
    }
  }

#pragma unroll
  for (int mb = 0; mb < 4; ++mb)
#pragma unroll
    for (int nb = 0; nb < 4; ++nb)
#pragma unroll
      for (int r = 0; r < 4; ++r) {
        int m = ar0 + wm + mb * 16 + kg * 4 + r;
        int n = br0 + wn + nb * 16 + rl;
        outp[(size_t)m * EMBED + n] = acc[mb][nb][r] + bias[n];
      }
}

// ---------------------------------------------------------------------------
// Flash attention, swapped-QK^T, fixed-exponent softmax (R15-green inner
// loop) — XCD-RESIDENT K/V:
//  * 1-D grid of 512; XCD-aware decode assuming round-robin bid%8:
//      bh = (bid&7)*4 + (bid>>7), qt = (bid>>3)&15
//    -> XCD i hosts exactly heads {4i..4i+3}: 2MB K/V < 4MB L2 (resident),
//    while 4 waves/block share each staged tile (halved L1->L2 traffic).
//  * s_setprio(1) around MFMA clusters (T5).
// P roundtrip + l-by-MFMA per wave identical to R12/R15-green.
// LDS: K dbuf 16KB + V dbuf 16KB + P 4x4KB = 48KB.
// ---------------------------------------------------------------------------
__global__ __launch_bounds__(256) void attn_kernel(
    const ushort_t* __restrict__ qp, const ushort_t* __restrict__ kp,
    const ushort_t* __restrict__ vtp, ushort_t* __restrict__ ao) {
  __shared__ __align__(16) unsigned char ldsK[2][8192];
  __shared__ __align__(16) unsigned char ldsV[2][8192];
  __shared__ __align__(16) unsigned char ldsP[4][4096];

  const int bid  = blockIdx.x;
  const int bh   = (bid & 7) * 4 + (bid >> 7); // XCD-resident head slice
  const int qt   = (bid >> 3) & 15;
  const int tid  = threadIdx.x;
  const int lane = tid & 63;
  const int w    = tid >> 6;                  // 0..3
  const int q0   = qt * 128 + w * 32;         // wave's q base
  const int rl   = lane & 15;
  const int kg   = lane >> 4;
  const int pswz = (rl & 7) << 4;

  const bf16x8 ones = __builtin_bit_cast(bf16x8,
      u32x4{0x3F803F80u, 0x3F803F80u, 0x3F803F80u, 0x3F803F80u});

  // Q fragments (B-operand): lane (rl,kg) holds Q[q=qb*16+rl][d=kk*32+kg*8..+8]
  bf16x8 qa[2][2];
#pragma unroll
  for (int qb = 0; qb < 2; ++qb)
#pragma unroll
    for (int kk = 0; kk < 2; ++kk)
      qa[qb][kk] = *(const bf16x8*)(qp + ((size_t)bh * S_ + q0 + qb * 16 + rl) * HDIM +
                                    kk * 32 + kg * 8);

  f32x4 o_acc[2][4];
  f32x4 o_l[2];
#pragma unroll
  for (int qb = 0; qb < 2; ++qb) {
#pragma unroll
    for (int nb = 0; nb < 4; ++nb) o_acc[qb][nb] = f32x4{0.f, 0.f, 0.f, 0.f};
    o_l[qb] = f32x4{0.f, 0.f, 0.f, 0.f};
  }

  unsigned char* pb = ldsP[w];

  // stage KV tile kt: 512 16B-units K + 512 V, 256 threads x 4 insts
  auto STAGE = [&](int kt, int bsel) {
#pragma unroll
    for (int s = 0; s < 4; ++s) {
      const int Lb = (s & 1) * 256 + w * 64;  // wave-uniform
      const int L = Lb + lane;
      const int row = L >> 3;
      const int gu = (L & 7) ^ (row & 7);
      if (s < 2) {
        GLOAD_LDS16(kp + ((size_t)bh * S_ + (size_t)kt * 64 + row) * HDIM + gu * 8,
                    &ldsK[bsel][Lb * 16]);
      } else {
        GLOAD_LDS16(vtp + ((size_t)bh * HDIM + row) * S_ + (size_t)kt * 64 + gu * 8,
                    &ldsV[bsel][Lb * 16]);
      }
    }
  };

  STAGE(0, 0);
  DRAIN_VM();
  __syncthreads();
  int cb = 0;
  for (int kt = 0; kt < 32; ++kt) {
    if (kt < 31) STAGE(kt + 1, cb ^ 1);

    // QK^T (swapped): sa[qb][nb][r] = S^T[key=nb*16+kg*4+r][q=qb*16+rl]
    f32x4 sa[2][4];
#pragma unroll
    for (int qb = 0; qb < 2; ++qb)
#pragma unroll
      for (int nb = 0; nb < 4; ++nb) sa[qb][nb] = f32x4{0.f, 0.f, 0.f, 0.f};
    __builtin_amdgcn_s_setprio(1);
#pragma unroll
    for (int nb = 0; nb < 4; ++nb) {
      const int row = nb * 16 + rl;
#pragma unroll
      for (int kk = 0; kk < 2; ++kk) {
        bf16x8 kf = *(const bf16x8*)(ldsK[cb] + row * 128 +
                                     ((kk * 64 + kg * 16) ^ ((row & 7) << 4)));
        sa[0][nb] = __builtin_amdgcn_mfma_f32_16x16x32_bf16(kf, qa[0][kk], sa[0][nb], 0, 0, 0);
        sa[1][nb] = __builtin_amdgcn_mfma_f32_16x16x32_bf16(kf, qa[1][kk], sa[1][nb], 0, 0, 0);
      }
    }
    __builtin_amdgcn_s_setprio(0);

    // P = exp2(s) -> bf16, packed 8B writes into per-wave LDS P buffer:
    // row = q = qb*16+rl; byte = key*2 ^ pswz  (key = nb*16+kg*4+r)
#pragma unroll
    for (int qb = 0; qb < 2; ++qb)
#pragma unroll
      for (int nb = 0; nb < 4; ++nb) {
        bf16x4 pk4;
#pragma unroll
        for (int r = 0; r < 4; ++r)
          pk4[r] = (__bf16)__builtin_amdgcn_exp2f(sa[qb][nb][r]);
        *(bf16x4*)(pb + (qb * 16 + rl) * 128 + ((nb * 32 + kg * 8) ^ pswz)) = pk4;
      }
    asm volatile("s_waitcnt lgkmcnt(0)" ::: "memory");
    __builtin_amdgcn_sched_barrier(0);

    // read P back as MFMA-A fragments: lane (rl,kg) row q, keys kk*32+kg*8..+7
    bf16x8 pa[2][2];
#pragma unroll
    for (int qb = 0; qb < 2; ++qb)
#pragma unroll
      for (int kk = 0; kk < 2; ++kk)
        pa[qb][kk] = *(const bf16x8*)(pb + (qb * 16 + rl) * 128 +
                                      ((kk * 64 + kg * 16) ^ pswz));

    __builtin_amdgcn_s_setprio(1);
    // l by MFMA: o_l[qb][r] = sum_k P[q][k]  (same bf16 P as PV -> consistent)
    o_l[0] = __builtin_amdgcn_mfma_f32_16x16x32_bf16(pa[0][0], ones, o_l[0], 0, 0, 0);
    o_l[0] = __builtin_amdgcn_mfma_f32_16x16x32_bf16(pa[0][1], ones, o_l[0], 0, 0, 0);
    o_l[1] = __builtin_amdgcn_mfma_f32_16x16x32_bf16(pa[1][0], ones, o_l[1], 0, 0, 0);
    o_l[1] = __builtin_amdgcn_mfma_f32_16x16x32_bf16(pa[1][1], ones, o_l[1], 0, 0, 0);

    // PV: O[q][d] += P[q][key] * V^T[d][key]
#pragma unroll
    for (int nb = 0; nb < 4; ++nb) {
      const int row = nb * 16 + rl;
#pragma unroll
      for (int kk = 0; kk < 2; ++kk) {
        bf16x8 vb = *(const bf16x8*)(ldsV[cb] + row * 128 +
                                     ((kk * 64 + kg * 16) ^ ((row & 7) << 4)));
        o_acc[0][nb] = __builtin_amdgcn_mfma_f32_16x16x32_bf16(pa[0][kk], vb, o_acc[0][nb], 0, 0, 0);
        o_acc[1][nb] = __builtin_amdgcn_mfma_f32_16x16x32_bf16(pa[1][kk], vb, o_acc[1][nb], 0, 0, 0);
      }
    }
    __builtin_amdgcn_s_setprio(0);

    DRAIN_VM();                       // prefetch landed before publish barrier
    __syncthreads();
    cb ^= 1;
  }

  // epilogue: O[q=qb*16+kg*4+r][d=nb*16+rl] / l[q]; o_l aligned with o_acc
  const int b = bh >> 4, h = bh & 15;
#pragma unroll
  for (int qb = 0; qb < 2; ++qb)
#pragma unroll
    for (int r = 0; r < 4; ++r) {
      float linv = 1.0f / o_l[qb][r];
      const int row = q0 + qb * 16 + kg * 4 + r;
#pragma unroll
      for (int nb = 0; nb < 4; ++nb) {
        float v = o_acc[qb][nb][r] * linv;
        ao[((size_t)b * S_ + row) * EMBED + h * HDIM + nb * 16 + rl] = f2bf(v);
      }
    }
}

// ---------------------------------------------------------------------------
extern "C" void kernel_launch(void* const* d_in, const int* in_sizes, int n_in,
                              void* d_out, int out_size, void* d_ws, size_t ws_size,
                              hipStream_t stream) {
  const float* x    = (const float*)d_in[0];
  const int*   mask = (const int*)d_in[1];
  const float* Wq   = (const float*)d_in[2];
  const float* bq   = (const float*)d_in[3];
  const float* Wk   = (const float*)d_in[4];
  const float* bk   = (const float*)d_in[5];
  const float* Wv   = (const float*)d_in[6];
  const float* bv   = (const float*)d_in[7];
  const float* Wo   = (const float*)d_in[8];
  const float* bo   = (const float*)d_in[9];

  char* ws = (char*)d_ws;
  ushort_t* xb  = (ushort_t*)(ws);
  ushort_t* wqb = (ushort_t*)(ws + 8388608);
  ushort_t* wkb = (ushort_t*)(ws + 10485760);
  ushort_t* wvb = (ushort_t*)(ws + 12582912);
  ushort_t* wob = (ushort_t*)(ws + 14680064);
  ushort_t* qb  = (ushort_t*)(ws + 16777216);
  ushort_t* kb  = (ushort_t*)(ws + 25165824);
  ushort_t* vtb = (ushort_t*)(ws + 33554432);
  ushort_t* aob = (ushort_t*)(ws + 41943040);

  hipLaunchKernelGGL(convert_kernel, dim3(8192), dim3(256), 0, stream,
                     x, Wq, Wk, Wv, Wo, xb, wqb, wkb, wvb, wob);
  hipLaunchKernelGGL(qkv_kernel, dim3(768), dim3(256), 0, stream,
                     xb, wqb, wkb, wvb, bq, bk, bv, mask, qb, kb, vtb);
  hipLaunchKernelGGL(attn_kernel, dim3(512), dim3(256), 0, stream,
                     qb, kb, vtb, aob);
  hipLaunchKernelGGL(gemm_o_kernel, dim3(32, 8), dim3(256), 0, stream,
                     aob, wob, bo, (float*)d_out);
}

// Round 21
// 117.213 us; speedup vs baseline: 1.5883x; 1.0164x over previous
//
#include <hip/hip_runtime.h>

#define DEV __device__ __forceinline__

typedef __bf16 bf16x8 __attribute__((ext_vector_type(8)));
typedef __bf16 bf16x4 __attribute__((ext_vector_type(4)));
typedef float f32x4 __attribute__((ext_vector_type(4)));
typedef unsigned u32x4 __attribute__((ext_vector_type(4)));
typedef unsigned short ushort_t;

static constexpr int EMBED = 1024;
static constexpr int NHEAD = 16;
static constexpr int HDIM  = 64;
static constexpr int S_    = 2048;
static constexpr float SCALE_L2E = 0.125f * 1.44269504088896340736f; // (1/sqrt(64))*log2(e)

DEV ushort_t f2bf(float f) {
  unsigned u = __builtin_bit_cast(unsigned, f);
  unsigned r = (u + 0x7fffu + ((u >> 16) & 1u)) >> 16;
  return (ushort_t)r;
}

// async global->LDS, 16B per lane; LDS dest is wave-uniform base + lane*16
#define GLOAD_LDS16(g, l)                                                   \
  __builtin_amdgcn_global_load_lds(                                         \
      (const __attribute__((address_space(1))) unsigned int*)(g),           \
      (__attribute__((address_space(3))) unsigned int*)(l), 16, 0, 0)

// explicit drain of global_load_lds before a publish barrier
#define DRAIN_VM() asm volatile("s_waitcnt vmcnt(0)" ::: "memory")

// ---------------------------------------------------------------------------
// fp32 -> bf16 conversion of x and the four weight matrices
// ---------------------------------------------------------------------------
__global__ __launch_bounds__(256) void convert_kernel(
    const float* __restrict__ x,
    const float* __restrict__ wq, const float* __restrict__ wk,
    const float* __restrict__ wv, const float* __restrict__ wo,
    ushort_t* __restrict__ xb, ushort_t* __restrict__ wqb,
    ushort_t* __restrict__ wkb, ushort_t* __restrict__ wvb,
    ushort_t* __restrict__ wob) {
  size_t i = ((size_t)blockIdx.x * blockDim.x + threadIdx.x) * 4;
  const float* src; ushort_t* dst; size_t off;
  if (i < 4194304u)      { src = x;  dst = xb;  off = i; }
  else if (i < 5242880u) { src = wq; dst = wqb; off = i - 4194304u; }
  else if (i < 6291456u) { src = wk; dst = wkb; off = i - 5242880u; }
  else if (i < 7340032u) { src = wv; dst = wvb; off = i - 6291456u; }
  else                   { src = wo; dst = wob; off = i - 7340032u; }
  float4 v = *(const float4*)(src + off);
  ushort4 o;
  o.x = f2bf(v.x); o.y = f2bf(v.y); o.z = f2bf(v.z); o.w = f2bf(v.w);
  *(ushort4*)(dst + off) = o;
}

// ---------------------------------------------------------------------------
// Merged QKV GEMM, 1-D grid of 768 blocks (R12-green single-buffer m97):
//   bid <256 : Q = xb @ Wq^T  -> [B,H,S,D], (acc+bias)*mask*SCALE_L2E
//   bid <512 : K = xb @ Wk^T  -> [B,H,S,D], (acc+bias)*mask
//   else     : V^T (A=Wv, B=xb) -> [B,H,D,S], acc+bias
// ---------------------------------------------------------------------------
__global__ __launch_bounds__(256) void qkv_kernel(
    const ushort_t* __restrict__ xb, const ushort_t* __restrict__ wqb,
    const ushort_t* __restrict__ wkb, const ushort_t* __restrict__ wvb,
    const float* __restrict__ bq, const float* __restrict__ bk,
    const float* __restrict__ bv, const int* __restrict__ mask,
    ushort_t* __restrict__ qo, ushort_t* __restrict__ ko,
    ushort_t* __restrict__ vto) {
  __shared__ __align__(16) unsigned char ldsA[16384];
  __shared__ __align__(16) unsigned char ldsB[16384];
  __shared__ float maskf[2][128];

  const int bid  = blockIdx.x;
  const int tid  = threadIdx.x;
  const int lane = tid & 63;
  const int w    = tid >> 6;
  const int wm   = (w >> 1) * 64;
  const int wn   = (w & 1) * 64;
  const int rl   = lane & 15;
  const int kg   = lane >> 4;

  int mode, ar0, br0;
  const ushort_t *A, *Bm;
  const float* bias;
  if (bid < 512) {
    mode = bid >> 8;                 // 0=Q, 1=K
    int t = bid & 255;
    ar0 = (t & 31) * 128;            // x rows
    br0 = (t >> 5) * 128;            // weight rows
    A = xb; Bm = mode ? wkb : wqb; bias = mode ? bk : bq;
  } else {
    mode = 2;
    int t = bid - 512;
    ar0 = (t & 7) * 128;             // weight rows
    br0 = (t >> 3) * 128;            // x rows
    A = wvb; Bm = xb; bias = bv;
  }

  if (mode < 2) {
    int hl = tid >> 7, sl = tid & 127;
    int m = ar0 + sl;
    int b = m >> 11, s = m & 2047;
    int h = (br0 >> 6) + hl;
    maskf[hl][sl] = (float)mask[((size_t)b * NHEAD + h) * S_ + s];
  }

  f32x4 acc[4][4];
#pragma unroll
  for (int i = 0; i < 4; ++i)
#pragma unroll
    for (int j = 0; j < 4; ++j) acc[i][j] = f32x4{0.f, 0.f, 0.f, 0.f};

  auto STAGE = [&](int kt) {
    const int k0 = kt * 64;
#pragma unroll
    for (int s = 0; s < 8; ++s) {
      const int basev = s * 256 + w * 64;   // wave-uniform
      const int Lb = basev & 1023;
      const int L = Lb + lane;
      const int row = L >> 3;
      const int gu = (L & 7) ^ (row & 7);
      if (s < 4) {
        GLOAD_LDS16(A + (size_t)(ar0 + row) * EMBED + k0 + gu * 8, &ldsA[Lb * 16]);
      } else {
        GLOAD_LDS16(Bm + (size_t)(br0 + row) * EMBED + k0 + gu * 8, &ldsB[Lb * 16]);
      }
    }
  };

  for (int kt = 0; kt < 16; ++kt) {
    if (kt) __syncthreads();          // all waves done reading previous tile
    STAGE(kt);
    DRAIN_VM();                       // my loads landed
    __syncthreads();                  // everyone's loads landed
#pragma unroll
    for (int kk = 0; kk < 2; ++kk) {
      bf16x8 af[4], bfr[4];
#pragma unroll
      for (int mb = 0; mb < 4; ++mb) {
        const int row = wm + mb * 16 + rl;
        const int off = (kk * 64 + kg * 16) ^ ((row & 7) << 4);
        af[mb] = *(const bf16x8*)(ldsA + row * 128 + off);
      }
#pragma unroll
      for (int nb = 0; nb < 4; ++nb) {
        const int row = wn + nb * 16 + rl;
        const int off = (kk * 64 + kg * 16) ^ ((row & 7) << 4);
        bfr[nb] = *(const bf16x8*)(ldsB + row * 128 + off);
      }
#pragma unroll
      for (int mb = 0; mb < 4; ++mb)
#pragma unroll
        for (int nb = 0; nb < 4; ++nb)
          acc[mb][nb] = __builtin_amdgcn_mfma_f32_16x16x32_bf16(
              af[mb], bfr[nb], acc[mb][nb], 0, 0, 0);
    }
  }

  // epilogue — D layout: row(A idx)=(lane>>4)*4+r, col(B idx)=lane&15
#pragma unroll
  for (int mb = 0; mb < 4; ++mb)
#pragma unroll
    for (int nb = 0; nb < 4; ++nb)
#pragma unroll
      for (int r = 0; r < 4; ++r) {
        int row_l = wm + mb * 16 + kg * 4 + r;
        int col_l = wn + nb * 16 + rl;
        float v = acc[mb][nb][r];
        if (mode < 2) {
          int m = ar0 + row_l, n = br0 + col_l;
          v = (v + bias[n]) * maskf[col_l >> 6][row_l];
          if (mode == 0) v *= SCALE_L2E;
          int b = m >> 11, s = m & 2047, h = n >> 6, d = n & 63;
          ushort_t* o = mode ? ko : qo;
          o[(((size_t)(b * NHEAD + h)) * S_ + s) * HDIM + d] = f2bf(v);
        } else {
          int n = ar0 + row_l, m = br0 + col_l;
          v += bias[n];
          int b = m >> 11, s = m & 2047, h = n >> 6, d = n & 63;
          vto[(((size_t)(b * NHEAD + h)) * HDIM + d) * S_ + s] = f2bf(v);
        }
      }
}

// ---------------------------------------------------------------------------
// O projection GEMM: out[m][n] = aob[m][:] . Wo[n][:] + bo[n]  (fp32 out)
// R12-green single-buffer m97 structure.
// ---------------------------------------------------------------------------
__global__ __launch_bounds__(256) void gemm_o_kernel(
    const ushort_t* __restrict__ A, const ushort_t* __restrict__ Bm,
    const float* __restrict__ bias, float* __restrict__ outp) {
  __shared__ __align__(16) unsigned char ldsA[16384];
  __shared__ __align__(16) unsigned char ldsB[16384];

  const int tid  = threadIdx.x;
  const int lane = tid & 63;
  const int w    = tid >> 6;
  const int ar0  = blockIdx.x * 128;
  const int br0  = blockIdx.y * 128;
  const int wm   = (w >> 1) * 64;
  const int wn   = (w & 1) * 64;
  const int rl   = lane & 15;
  const int kg   = lane >> 4;

  f32x4 acc[4][4];
#pragma unroll
  for (int i = 0; i < 4; ++i)
#pragma unroll
    for (int j = 0; j < 4; ++j) acc[i][j] = f32x4{0.f, 0.f, 0.f, 0.f};

  auto STAGE = [&](int kt) {
    const int k0 = kt * 64;
#pragma unroll
    for (int s = 0; s < 8; ++s) {
      const int basev = s * 256 + w * 64;
      const int Lb = basev & 1023;
      const int L = Lb + lane;
      const int row = L >> 3;
      const int gu = (L & 7) ^ (row & 7);
      if (s < 4) {
        GLOAD_LDS16(A + (size_t)(ar0 + row) * EMBED + k0 + gu * 8, &ldsA[Lb * 16]);
      } else {
        GLOAD_LDS16(Bm + (size_t)(br0 + row) * EMBED + k0 + gu * 8, &ldsB[Lb * 16]);
      }
    }
  };

  for (int kt = 0; kt < 16; ++kt) {
    if (kt) __syncthreads();
    STAGE(kt);
    DRAIN_VM();
    __syncthreads();
#pragma unroll
    for (int kk = 0; kk < 2; ++kk) {
      bf16x8 af[4], bfr[4];
#pragma unroll
      for (int mb = 0; mb < 4; ++mb) {
        const int row = wm + mb * 16 + rl;
        const int off = (kk * 64 + kg * 16) ^ ((row & 7) << 4);
        af[mb] = *(const bf16x8*)(ldsA + row * 128 + off);
      }
#pragma unroll
      for (int nb = 0; nb < 4; ++nb) {
        const int row = wn + nb * 16 + rl;
        const int off = (kk * 64 + kg * 16) ^ ((row & 7) << 4);
        bfr[nb] = *(const bf16x8*)(ldsB + row * 128 + off);
      }
#pragma unroll
      for (int mb = 0; mb < 4; ++mb)
#pragma unroll
        for (int nb = 0; nb < 4; ++nb)
          acc[mb][nb] = __builtin_amdgcn_mfma_f32_16x16x32_bf16(
              af[mb], bfr[nb], acc[mb][nb], 0, 0, 0);
    }
  }

#pragma unroll
  for (int mb = 0; mb < 4; ++mb)
#pragma unroll
    for (int nb = 0; nb < 4; ++nb)
#pragma unroll
      for (int r = 0; r < 4; ++r) {
        int m = ar0 + wm + mb * 16 + kg * 4 + r;
        int n = br0 + wn + nb * 16 + rl;
        outp[(size_t)m * EMBED + n] = acc[mb][nb][r] + bias[n];
      }
}

// ---------------------------------------------------------------------------
// Flash attention, swapped-QK^T, fixed-exponent softmax — 3-BUFFER
// COUNTED-VMCNT PIPELINE (T3/T4):
//  * K/V rotate through 3 LDS buffers; STAGE(kt+2) issued at body top;
//    before the publish barrier wait only vmcnt(4) (the just-issued 4 stay
//    in flight) — tile kt+1 was issued a full iteration ago and is landed.
//  * raw s_barrier + explicit waitcnt (NOT __syncthreads, which would
//    re-insert the vmcnt(0) drain); lgkmcnt(0) covers cross-wave LDS
//    read-before-overwrite (buffer cur is overwritten at kt+3's STAGE,
//    two barriers later -> no rotation hazard).
//  * XCD-aware decode (bh=(bid&7)*4+(bid>>7)) keeps K/V L2-resident;
//    4 waves share each staged tile; s_setprio around MFMA clusters.
// P roundtrip + l-by-MFMA per wave identical to R17-green.
// LDS: K 3x8KB + V 3x8KB + P 4x4KB = 64KB -> 2 blocks/CU (grid-limited).
// ---------------------------------------------------------------------------
__global__ __launch_bounds__(256) void attn_kernel(
    const ushort_t* __restrict__ qp, const ushort_t* __restrict__ kp,
    const ushort_t* __restrict__ vtp, ushort_t* __restrict__ ao) {
  __shared__ __align__(16) unsigned char ldsK[3][8192];
  __shared__ __align__(16) unsigned char ldsV[3][8192];
  __shared__ __align__(16) unsigned char ldsP[4][4096];

  const int bid  = blockIdx.x;
  const int bh   = (bid & 7) * 4 + (bid >> 7); // XCD-resident head slice
  const int qt   = (bid >> 3) & 15;
  const int tid  = threadIdx.x;
  const int lane = tid & 63;
  const int w    = tid >> 6;                  // 0..3
  const int q0   = qt * 128 + w * 32;         // wave's q base
  const int rl   = lane & 15;
  const int kg   = lane >> 4;
  const int pswz = (rl & 7) << 4;

  const bf16x8 ones = __builtin_bit_cast(bf16x8,
      u32x4{0x3F803F80u, 0x3F803F80u, 0x3F803F80u, 0x3F803F80u});

  // Q fragments (B-operand): lane (rl,kg) holds Q[q=qb*16+rl][d=kk*32+kg*8..+8]
  bf16x8 qa[2][2];
#pragma unroll
  for (int qb = 0; qb < 2; ++qb)
#pragma unroll
    for (int kk = 0; kk < 2; ++kk)
      qa[qb][kk] = *(const bf16x8*)(qp + ((size_t)bh * S_ + q0 + qb * 16 + rl) * HDIM +
                                    kk * 32 + kg * 8);

  f32x4 o_acc[2][4];
  f32x4 o_l[2];
#pragma unroll
  for (int qb = 0; qb < 2; ++qb) {
#pragma unroll
    for (int nb = 0; nb < 4; ++nb) o_acc[qb][nb] = f32x4{0.f, 0.f, 0.f, 0.f};
    o_l[qb] = f32x4{0.f, 0.f, 0.f, 0.f};
  }

  unsigned char* pb = ldsP[w];

  // stage KV tile kt into slot: 512 16B-units K + 512 V, 4 insts/thread
  auto STAGE = [&](int kt, int slot) {
#pragma unroll
    for (int s = 0; s < 4; ++s) {
      const int Lb = (s & 1) * 256 + w * 64;  // wave-uniform
      const int L = Lb + lane;
      const int row = L >> 3;
      const int gu = (L & 7) ^ (row & 7);
      if (s < 2) {
        GLOAD_LDS16(kp + ((size_t)bh * S_ + (size_t)kt * 64 + row) * HDIM + gu * 8,
                    &ldsK[slot][Lb * 16]);
      } else {
        GLOAD_LDS16(vtp + ((size_t)bh * HDIM + row) * S_ + (size_t)kt * 64 + gu * 8,
                    &ldsV[slot][Lb * 16]);
      }
    }
  };

  STAGE(0, 0);
  STAGE(1, 1);
  asm volatile("s_waitcnt vmcnt(4) lgkmcnt(0)" ::: "memory"); // tile 0 landed
  __builtin_amdgcn_s_barrier();
  int cur = 0;
  for (int kt = 0; kt < 32; ++kt) {
    if (kt + 2 < 32) {
      int slot = cur + 2; if (slot >= 3) slot -= 3;
      STAGE(kt + 2, slot);                    // 2-deep prefetch
    }

    // QK^T (swapped): sa[qb][nb][r] = S^T[key=nb*16+kg*4+r][q=qb*16+rl]
    f32x4 sa[2][4];
#pragma unroll
    for (int qb = 0; qb < 2; ++qb)
#pragma unroll
      for (int nb = 0; nb < 4; ++nb) sa[qb][nb] = f32x4{0.f, 0.f, 0.f, 0.f};
    __builtin_amdgcn_s_setprio(1);
#pragma unroll
    for (int nb = 0; nb < 4; ++nb) {
      const int row = nb * 16 + rl;
#pragma unroll
      for (int kk = 0; kk < 2; ++kk) {
        bf16x8 kf = *(const bf16x8*)(ldsK[cur] + row * 128 +
                                     ((kk * 64 + kg * 16) ^ ((row & 7) << 4)));
        sa[0][nb] = __builtin_amdgcn_mfma_f32_16x16x32_bf16(kf, qa[0][kk], sa[0][nb], 0, 0, 0);
        sa[1][nb] = __builtin_amdgcn_mfma_f32_16x16x32_bf16(kf, qa[1][kk], sa[1][nb], 0, 0, 0);
      }
    }
    __builtin_amdgcn_s_setprio(0);

    // P = exp2(s) -> bf16, packed 8B writes into per-wave LDS P buffer:
    // row = q = qb*16+rl; byte = key*2 ^ pswz  (key = nb*16+kg*4+r)
#pragma unroll
    for (int qb = 0; qb < 2; ++qb)
#pragma unroll
      for (int nb = 0; nb < 4; ++nb) {
        bf16x4 pk4;
#pragma unroll
        for (int r = 0; r < 4; ++r)
          pk4[r] = (__bf16)__builtin_amdgcn_exp2f(sa[qb][nb][r]);
        *(bf16x4*)(pb + (qb * 16 + rl) * 128 + ((nb * 32 + kg * 8) ^ pswz)) = pk4;
      }
    asm volatile("s_waitcnt lgkmcnt(0)" ::: "memory");
    __builtin_amdgcn_sched_barrier(0);

    // read P back as MFMA-A fragments: lane (rl,kg) row q, keys kk*32+kg*8..+7
    bf16x8 pa[2][2];
#pragma unroll
    for (int qb = 0; qb < 2; ++qb)
#pragma unroll
      for (int kk = 0; kk < 2; ++kk)
        pa[qb][kk] = *(const bf16x8*)(pb + (qb * 16 + rl) * 128 +
                                      ((kk * 64 + kg * 16) ^ pswz));

    __builtin_amdgcn_s_setprio(1);
    // l by MFMA: o_l[qb][r] = sum_k P[q][k]  (same bf16 P as PV -> consistent)
    o_l[0] = __builtin_amdgcn_mfma_f32_16x16x32_bf16(pa[0][0], ones, o_l[0], 0, 0, 0);
    o_l[0] = __builtin_amdgcn_mfma_f32_16x16x32_bf16(pa[0][1], ones, o_l[0], 0, 0, 0);
    o_l[1] = __builtin_amdgcn_mfma_f32_16x16x32_bf16(pa[1][0], ones, o_l[1], 0, 0, 0);
    o_l[1] = __builtin_amdgcn_mfma_f32_16x16x32_bf16(pa[1][1], ones, o_l[1], 0, 0, 0);

    // PV: O[q][d] += P[q][key] * V^T[d][key]
#pragma unroll
    for (int nb = 0; nb < 4; ++nb) {
      const int row = nb * 16 + rl;
#pragma unroll
      for (int kk = 0; kk < 2; ++kk) {
        bf16x8 vb = *(const bf16x8*)(ldsV[cur] + row * 128 +
                                     ((kk * 64 + kg * 16) ^ ((row & 7) << 4)));
        o_acc[0][nb] = __builtin_amdgcn_mfma_f32_16x16x32_bf16(pa[0][kk], vb, o_acc[0][nb], 0, 0, 0);
        o_acc[1][nb] = __builtin_amdgcn_mfma_f32_16x16x32_bf16(pa[1][kk], vb, o_acc[1][nb], 0, 0, 0);
      }
    }
    __builtin_amdgcn_s_setprio(0);

    // publish next buffer: tile kt+1 landed (issued a full iteration ago);
    // the 4 loads of STAGE(kt+2) may stay in flight (counted vmcnt).
    if (kt + 2 < 32) {
      asm volatile("s_waitcnt vmcnt(4) lgkmcnt(0)" ::: "memory");
    } else {
      asm volatile("s_waitcnt vmcnt(0) lgkmcnt(0)" ::: "memory");
    }
    __builtin_amdgcn_s_barrier();
    cur = (cur == 2) ? 0 : cur + 1;
  }

  // epilogue: O[q=qb*16+kg*4+r][d=nb*16+rl] / l[q]; o_l aligned with o_acc
  const int b = bh >> 4, h = bh & 15;
#pragma unroll
  for (int qb = 0; qb < 2; ++qb)
#pragma unroll
    for (int r = 0; r < 4; ++r) {
      float linv = 1.0f / o_l[qb][r];
      const int row = q0 + qb * 16 + kg * 4 + r;
#pragma unroll
      for (int nb = 0; nb < 4; ++nb) {
        float v = o_acc[qb][nb][r] * linv;
        ao[((size_t)b * S_ + row) * EMBED + h * HDIM + nb * 16 + rl] = f2bf(v);
      }
    }
}

// ---------------------------------------------------------------------------
extern "C" void kernel_launch(void* const* d_in, const int* in_sizes, int n_in,
                              void* d_out, int out_size, void* d_ws, size_t ws_size,
                              hipStream_t stream) {
  const float* x    = (const float*)d_in[0];
  const int*   mask = (const int*)d_in[1];
  const float* Wq   = (const float*)d_in[2];
  const float* bq   = (const float*)d_in[3];
  const float* Wk   = (const float*)d_in[4];
  const float* bk   = (const float*)d_in[5];
  const float* Wv   = (const float*)d_in[6];
  const float* bv   = (const float*)d_in[7];
  const float* Wo   = (const float*)d_in[8];
  const float* bo   = (const float*)d_in[9];

  char* ws = (char*)d_ws;
  ushort_t* xb  = (ushort_t*)(ws);
  ushort_t* wqb = (ushort_t*)(ws + 8388608);
  ushort_t* wkb = (ushort_t*)(ws + 10485760);
  ushort_t* wvb = (ushort_t*)(ws + 12582912);
  ushort_t* wob = (ushort_t*)(ws + 14680064);
  ushort_t* qb  = (ushort_t*)(ws + 16777216);
  ushort_t* kb  = (ushort_t*)(ws + 25165824);
  ushort_t* vtb = (ushort_t*)(ws + 33554432);
  ushort_t* aob = (ushort_t*)(ws + 41943040);

  hipLaunchKernelGGL(convert_kernel, dim3(8192), dim3(256), 0, stream,
                     x, Wq, Wk, Wv, Wo, xb, wqb, wkb, wvb, wob);
  hipLaunchKernelGGL(qkv_kernel, dim3(768), dim3(256), 0, stream,
                     xb, wqb, wkb, wvb, bq, bk, bv, mask, qb, kb, vtb);
  hipLaunchKernelGGL(attn_kernel, dim3(512), dim3(256), 0, stream,
                     qb, kb, vtb, aob);
  hipLaunchKernelGGL(gemm_o_kernel, dim3(32, 8), dim3(256), 0, stream,
                     aob, wob, bo, (float*)d_out);
}

// Round 22
// 115.178 us; speedup vs baseline: 1.6163x; 1.0177x over previous
//
#include <hip/hip_runtime.h>

#define DEV __device__ __forceinline__

typedef __bf16 bf16x8 __attribute__((ext_vector_type(8)));
typedef __bf16 bf16x4 __attribute__((ext_vector_type(4)));
typedef float f32x4 __attribute__((ext_vector_type(4)));
typedef unsigned u32x4 __attribute__((ext_vector_type(4)));
typedef unsigned short ushort_t;

static constexpr int EMBED = 1024;
static constexpr int NHEAD = 16;
static constexpr int HDIM  = 64;
static constexpr int S_    = 2048;
static constexpr float SCALE_L2E = 0.125f * 1.44269504088896340736f; // (1/sqrt(64))*log2(e)

DEV ushort_t f2bf(float f) {
  unsigned u = __builtin_bit_cast(unsigned, f);
  unsigned r = (u + 0x7fffu + ((u >> 16) & 1u)) >> 16;
  return (ushort_t)r;
}

// async global->LDS, 16B per lane; LDS dest is wave-uniform base + lane*16
#define GLOAD_LDS16(g, l)                                                   \
  __builtin_amdgcn_global_load_lds(                                         \
      (const __attribute__((address_space(1))) unsigned int*)(g),           \
      (__attribute__((address_space(3))) unsigned int*)(l), 16, 0, 0)

// explicit drain of global_load_lds before a publish barrier
#define DRAIN_VM() asm volatile("s_waitcnt vmcnt(0)" ::: "memory")

// ---------------------------------------------------------------------------
// fp32 -> bf16 conversion of x and the four weight matrices
// ---------------------------------------------------------------------------
__global__ __launch_bounds__(256) void convert_kernel(
    const float* __restrict__ x,
    const float* __restrict__ wq, const float* __restrict__ wk,
    const float* __restrict__ wv, const float* __restrict__ wo,
    ushort_t* __restrict__ xb, ushort_t* __restrict__ wqb,
    ushort_t* __restrict__ wkb, ushort_t* __restrict__ wvb,
    ushort_t* __restrict__ wob) {
  size_t i = ((size_t)blockIdx.x * blockDim.x + threadIdx.x) * 4;
  const float* src; ushort_t* dst; size_t off;
  if (i < 4194304u)      { src = x;  dst = xb;  off = i; }
  else if (i < 5242880u) { src = wq; dst = wqb; off = i - 4194304u; }
  else if (i < 6291456u) { src = wk; dst = wkb; off = i - 5242880u; }
  else if (i < 7340032u) { src = wv; dst = wvb; off = i - 6291456u; }
  else                   { src = wo; dst = wob; off = i - 7340032u; }
  float4 v = *(const float4*)(src + off);
  ushort4 o;
  o.x = f2bf(v.x); o.y = f2bf(v.y); o.z = f2bf(v.z); o.w = f2bf(v.w);
  *(ushort4*)(dst + off) = o;
}

// ---------------------------------------------------------------------------
// Merged QKV GEMM, 1-D grid of 768 blocks (R12-green single-buffer m97):
//   bid <256 : Q = xb @ Wq^T  -> [B,H,S,D], (acc+bias)*mask*SCALE_L2E
//   bid <512 : K = xb @ Wk^T  -> [B,H,S,D], (acc+bias)*mask
//   else     : V^T (A=Wv, B=xb) -> [B,H,D,S], acc+bias
// ---------------------------------------------------------------------------
__global__ __launch_bounds__(256) void qkv_kernel(
    const ushort_t* __restrict__ xb, const ushort_t* __restrict__ wqb,
    const ushort_t* __restrict__ wkb, const ushort_t* __restrict__ wvb,
    const float* __restrict__ bq, const float* __restrict__ bk,
    const float* __restrict__ bv, const int* __restrict__ mask,
    ushort_t* __restrict__ qo, ushort_t* __restrict__ ko,
    ushort_t* __restrict__ vto) {
  __shared__ __align__(16) unsigned char ldsA[16384];
  __shared__ __align__(16) unsigned char ldsB[16384];
  __shared__ float maskf[2][128];

  const int bid  = blockIdx.x;
  const int tid  = threadIdx.x;
  const int lane = tid & 63;
  const int w    = tid >> 6;
  const int wm   = (w >> 1) * 64;
  const int wn   = (w & 1) * 64;
  const int rl   = lane & 15;
  const int kg   = lane >> 4;

  int mode, ar0, br0;
  const ushort_t *A, *Bm;
  const float* bias;
  if (bid < 512) {
    mode = bid >> 8;                 // 0=Q, 1=K
    int t = bid & 255;
    ar0 = (t & 31) * 128;            // x rows
    br0 = (t >> 5) * 128;            // weight rows
    A = xb; Bm = mode ? wkb : wqb; bias = mode ? bk : bq;
  } else {
    mode = 2;
    int t = bid - 512;
    ar0 = (t & 7) * 128;             // weight rows
    br0 = (t >> 3) * 128;            // x rows
    A = wvb; Bm = xb; bias = bv;
  }

  if (mode < 2) {
    int hl = tid >> 7, sl = tid & 127;
    int m = ar0 + sl;
    int b = m >> 11, s = m & 2047;
    int h = (br0 >> 6) + hl;
    maskf[hl][sl] = (float)mask[((size_t)b * NHEAD + h) * S_ + s];
  }

  f32x4 acc[4][4];
#pragma unroll
  for (int i = 0; i < 4; ++i)
#pragma unroll
    for (int j = 0; j < 4; ++j) acc[i][j] = f32x4{0.f, 0.f, 0.f, 0.f};

  auto STAGE = [&](int kt) {
    const int k0 = kt * 64;
#pragma unroll
    for (int s = 0; s < 8; ++s) {
      const int basev = s * 256 + w * 64;   // wave-uniform
      const int Lb = basev & 1023;
      const int L = Lb + lane;
      const int row = L >> 3;
      const int gu = (L & 7) ^ (row & 7);
      if (s < 4) {
        GLOAD_LDS16(A + (size_t)(ar0 + row) * EMBED + k0 + gu * 8, &ldsA[Lb * 16]);
      } else {
        GLOAD_LDS16(Bm + (size_t)(br0 + row) * EMBED + k0 + gu * 8, &ldsB[Lb * 16]);
      }
    }
  };

  for (int kt = 0; kt < 16; ++kt) {
    if (kt) __syncthreads();          // all waves done reading previous tile
    STAGE(kt);
    DRAIN_VM();                       // my loads landed
    __syncthreads();                  // everyone's loads landed
#pragma unroll
    for (int kk = 0; kk < 2; ++kk) {
      bf16x8 af[4], bfr[4];
#pragma unroll
      for (int mb = 0; mb < 4; ++mb) {
        const int row = wm + mb * 16 + rl;
        const int off = (kk * 64 + kg * 16) ^ ((row & 7) << 4);
        af[mb] = *(const bf16x8*)(ldsA + row * 128 + off);
      }
#pragma unroll
      for (int nb = 0; nb < 4; ++nb) {
        const int row = wn + nb * 16 + rl;
        const int off = (kk * 64 + kg * 16) ^ ((row & 7) << 4);
        bfr[nb] = *(const bf16x8*)(ldsB + row * 128 + off);
      }
#pragma unroll
      for (int mb = 0; mb < 4; ++mb)
#pragma unroll
        for (int nb = 0; nb < 4; ++nb)
          acc[mb][nb] = __builtin_amdgcn_mfma_f32_16x16x32_bf16(
              af[mb], bfr[nb], acc[mb][nb], 0, 0, 0);
    }
  }

  // epilogue — D layout: row(A idx)=(lane>>4)*4+r, col(B idx)=lane&15
#pragma unroll
  for (int mb = 0; mb < 4; ++mb)
#pragma unroll
    for (int nb = 0; nb < 4; ++nb)
#pragma unroll
      for (int r = 0; r < 4; ++r) {
        int row_l = wm + mb * 16 + kg * 4 + r;
        int col_l = wn + nb * 16 + rl;
        float v = acc[mb][nb][r];
        if (mode < 2) {
          int m = ar0 + row_l, n = br0 + col_l;
          v = (v + bias[n]) * maskf[col_l >> 6][row_l];
          if (mode == 0) v *= SCALE_L2E;
          int b = m >> 11, s = m & 2047, h = n >> 6, d = n & 63;
          ushort_t* o = mode ? ko : qo;
          o[(((size_t)(b * NHEAD + h)) * S_ + s) * HDIM + d] = f2bf(v);
        } else {
          int n = ar0 + row_l, m = br0 + col_l;
          v += bias[n];
          int b = m >> 11, s = m & 2047, h = n >> 6, d = n & 63;
          vto[(((size_t)(b * NHEAD + h)) * HDIM + d) * S_ + s] = f2bf(v);
        }
      }
}

// ---------------------------------------------------------------------------
// O projection GEMM: out[m][n] = aob[m][:] . Wo[n][:] + bo[n]  (fp32 out)
// R12-green single-buffer m97 structure.
// ---------------------------------------------------------------------------
__global__ __launch_bounds__(256) void gemm_o_kernel(
    const ushort_t* __restrict__ A, const ushort_t* __restrict__ Bm,
    const float* __restrict__ bias, float* __restrict__ outp) {
  __shared__ __align__(16) unsigned char ldsA[16384];
  __shared__ __align__(16) unsigned char ldsB[16384];

  const int tid  = threadIdx.x;
  const int lane = tid & 63;
  const int w    = tid >> 6;
  const int ar0  = blockIdx.x * 128;
  const int br0  = blockIdx.y * 128;
  const int wm   = (w >> 1) * 64;
  const int wn   = (w & 1) * 64;
  const int rl   = lane & 15;
  const int kg   = lane >> 4;

  f32x4 acc[4][4];
#pragma unroll
  for (int i = 0; i < 4; ++i)
#pragma unroll
    for (int j = 0; j < 4; ++j) acc[i][j] = f32x4{0.f, 0.f, 0.f, 0.f};

  auto STAGE = [&](int kt) {
    const int k0 = kt * 64;
#pragma unroll
    for (int s = 0; s < 8; ++s) {
      const int basev = s * 256 + w * 64;
      const int Lb = basev & 1023;
      const int L = Lb + lane;
      const int row = L >> 3;
      const int gu = (L & 7) ^ (row & 7);
      if (s < 4) {
        GLOAD_LDS16(A + (size_t)(ar0 + row) * EMBED + k0 + gu * 8, &ldsA[Lb * 16]);
      } else {
        GLOAD_LDS16(Bm + (size_t)(br0 + row) * EMBED + k0 + gu * 8, &ldsB[Lb * 16]);
      }
    }
  };

  for (int kt = 0; kt < 16; ++kt) {
    if (kt) __syncthreads();
    STAGE(kt);
    DRAIN_VM();
    __syncthreads();
#pragma unroll
    for (int kk = 0; kk < 2; ++kk) {
      bf16x8 af[4], bfr[4];
#pragma unroll
      for (int mb = 0; mb < 4; ++mb) {
        const int row = wm + mb * 16 + rl;
        const int off = (kk * 64 + kg * 16) ^ ((row & 7) << 4);
        af[mb] = *(const bf16x8*)(ldsA + row * 128 + off);
      }
#pragma unroll
      for (int nb = 0; nb < 4; ++nb) {
        const int row = wn + nb * 16 + rl;
        const int off = (kk * 64 + kg * 16) ^ ((row & 7) << 4);
        bfr[nb] = *(const bf16x8*)(ldsB + row * 128 + off);
      }
#pragma unroll
      for (int mb = 0; mb < 4; ++mb)
#pragma unroll
        for (int nb = 0; nb < 4; ++nb)
          acc[mb][nb] = __builtin_amdgcn_mfma_f32_16x16x32_bf16(
              af[mb], bfr[nb], acc[mb][nb], 0, 0, 0);
    }
  }

#pragma unroll
  for (int mb = 0; mb < 4; ++mb)
#pragma unroll
    for (int nb = 0; nb < 4; ++nb)
#pragma unroll
      for (int r = 0; r < 4; ++r) {
        int m = ar0 + wm + mb * 16 + kg * 4 + r;
        int n = br0 + wn + nb * 16 + rl;
        outp[(size_t)m * EMBED + n] = acc[mb][nb][r] + bias[n];
      }
}

// ---------------------------------------------------------------------------
// Flash attention, swapped-QK^T, fixed-exponent softmax — 8 WAVES x 16 q
// (4 waves/SIMD occupancy; serial QK->exp2->P->PV chain per wave halves
// and 4-way wave interleave hides ds/trans latency), 3-BUFFER COUNTED-VMCNT
// pipeline (T3/T4), XCD-resident decode, s_setprio around MFMA clusters.
//  * 512 threads/block; STAGE = 2 insts/thread (512 K units + 512 V units);
//    prologue waits vmcnt(2); steady-state publish waits vmcnt(2)
//    (the 2 just-issued loads stay in flight); epilogue vmcnt(0).
//  * raw s_barrier + explicit waitcnt; slot overwritten 2 barriers after
//    its last read -> no rotation hazard.
// P roundtrip + l-by-MFMA unchanged in math; per-wave P is 16 rows (2KB).
// LDS: K 3x8KB + V 3x8KB + P 8x2KB = 64KB -> 2 blocks/CU (grid-limited).
// ---------------------------------------------------------------------------
__global__ __launch_bounds__(512) void attn_kernel(
    const ushort_t* __restrict__ qp, const ushort_t* __restrict__ kp,
    const ushort_t* __restrict__ vtp, ushort_t* __restrict__ ao) {
  __shared__ __align__(16) unsigned char ldsK[3][8192];
  __shared__ __align__(16) unsigned char ldsV[3][8192];
  __shared__ __align__(16) unsigned char ldsP[8][2048];

  const int bid  = blockIdx.x;
  const int bh   = (bid & 7) * 4 + (bid >> 7); // XCD-resident head slice
  const int qt   = (bid >> 3) & 15;
  const int tid  = threadIdx.x;
  const int lane = tid & 63;
  const int w    = tid >> 6;                  // 0..7
  const int q0   = qt * 128 + w * 16;         // wave's q base (16 rows)
  const int rl   = lane & 15;
  const int kg   = lane >> 4;
  const int pswz = (rl & 7) << 4;

  const bf16x8 ones = __builtin_bit_cast(bf16x8,
      u32x4{0x3F803F80u, 0x3F803F80u, 0x3F803F80u, 0x3F803F80u});

  // Q fragments (B-operand): lane (rl,kg) holds Q[q=rl][d=kk*32+kg*8..+8]
  bf16x8 qa[2];
#pragma unroll
  for (int kk = 0; kk < 2; ++kk)
    qa[kk] = *(const bf16x8*)(qp + ((size_t)bh * S_ + q0 + rl) * HDIM +
                              kk * 32 + kg * 8);

  f32x4 o_acc[4];
  f32x4 o_l = f32x4{0.f, 0.f, 0.f, 0.f};
#pragma unroll
  for (int nb = 0; nb < 4; ++nb) o_acc[nb] = f32x4{0.f, 0.f, 0.f, 0.f};

  unsigned char* pb = ldsP[w];

  // stage KV tile kt into slot: 512 K units + 512 V units, 2 insts/thread
  auto STAGE = [&](int kt, int slot) {
#pragma unroll
    for (int s = 0; s < 2; ++s) {
      const int Lb = w * 64;                  // wave-uniform, 8 waves x 64
      const int L = Lb + lane;
      const int row = L >> 3;
      const int gu = (L & 7) ^ (row & 7);
      if (s == 0) {
        GLOAD_LDS16(kp + ((size_t)bh * S_ + (size_t)kt * 64 + row) * HDIM + gu * 8,
                    &ldsK[slot][L * 16]);
      } else {
        GLOAD_LDS16(vtp + ((size_t)bh * HDIM + row) * S_ + (size_t)kt * 64 + gu * 8,
                    &ldsV[slot][L * 16]);
      }
    }
  };

  STAGE(0, 0);
  STAGE(1, 1);
  asm volatile("s_waitcnt vmcnt(2) lgkmcnt(0)" ::: "memory"); // tile 0 landed
  __builtin_amdgcn_s_barrier();
  int cur = 0;
  for (int kt = 0; kt < 32; ++kt) {
    if (kt + 2 < 32) {
      int slot = cur + 2; if (slot >= 3) slot -= 3;
      STAGE(kt + 2, slot);                    // 2-deep prefetch
    }

    // QK^T (swapped): sa[nb][r] = S^T[key=nb*16+kg*4+r][q=rl]
    f32x4 sa[4];
#pragma unroll
    for (int nb = 0; nb < 4; ++nb) sa[nb] = f32x4{0.f, 0.f, 0.f, 0.f};
    __builtin_amdgcn_s_setprio(1);
#pragma unroll
    for (int nb = 0; nb < 4; ++nb) {
      const int row = nb * 16 + rl;
#pragma unroll
      for (int kk = 0; kk < 2; ++kk) {
        bf16x8 kf = *(const bf16x8*)(ldsK[cur] + row * 128 +
                                     ((kk * 64 + kg * 16) ^ ((row & 7) << 4)));
        sa[nb] = __builtin_amdgcn_mfma_f32_16x16x32_bf16(kf, qa[kk], sa[nb], 0, 0, 0);
      }
    }
    __builtin_amdgcn_s_setprio(0);

    // P = exp2(s) -> bf16, packed 8B writes into per-wave LDS P buffer:
    // row = q = rl; byte = key*2 ^ pswz  (key = nb*16+kg*4+r)
#pragma unroll
    for (int nb = 0; nb < 4; ++nb) {
      bf16x4 pk4;
#pragma unroll
      for (int r = 0; r < 4; ++r)
        pk4[r] = (__bf16)__builtin_amdgcn_exp2f(sa[nb][r]);
      *(bf16x4*)(pb + rl * 128 + ((nb * 32 + kg * 8) ^ pswz)) = pk4;
    }
    asm volatile("s_waitcnt lgkmcnt(0)" ::: "memory");
    __builtin_amdgcn_sched_barrier(0);

    // read P back as MFMA-A fragments: lane (rl,kg) row q, keys kk*32+kg*8..+7
    bf16x8 pa[2];
#pragma unroll
    for (int kk = 0; kk < 2; ++kk)
      pa[kk] = *(const bf16x8*)(pb + rl * 128 + ((kk * 64 + kg * 16) ^ pswz));

    __builtin_amdgcn_s_setprio(1);
    // l by MFMA: o_l[r] = sum_k P[q][k]  (same bf16 P as PV -> consistent)
    o_l = __builtin_amdgcn_mfma_f32_16x16x32_bf16(pa[0], ones, o_l, 0, 0, 0);
    o_l = __builtin_amdgcn_mfma_f32_16x16x32_bf16(pa[1], ones, o_l, 0, 0, 0);

    // PV: O[q][d] += P[q][key] * V^T[d][key]
#pragma unroll
    for (int nb = 0; nb < 4; ++nb) {
      const int row = nb * 16 + rl;
#pragma unroll
      for (int kk = 0; kk < 2; ++kk) {
        bf16x8 vb = *(const bf16x8*)(ldsV[cur] + row * 128 +
                                     ((kk * 64 + kg * 16) ^ ((row & 7) << 4)));
        o_acc[nb] = __builtin_amdgcn_mfma_f32_16x16x32_bf16(pa[kk], vb, o_acc[nb], 0, 0, 0);
      }
    }
    __builtin_amdgcn_s_setprio(0);

    // publish next buffer: tile kt+1 landed (issued a full iteration ago);
    // the 2 loads of STAGE(kt+2) may stay in flight (counted vmcnt).
    if (kt + 2 < 32) {
      asm volatile("s_waitcnt vmcnt(2) lgkmcnt(0)" ::: "memory");
    } else {
      asm volatile("s_waitcnt vmcnt(0) lgkmcnt(0)" ::: "memory");
    }
    __builtin_amdgcn_s_barrier();
    cur = (cur == 2) ? 0 : cur + 1;
  }

  // epilogue: O[q=kg*4+r][d=nb*16+rl] / l[q]; o_l aligned with o_acc
  const int b = bh >> 4, h = bh & 15;
#pragma unroll
  for (int r = 0; r < 4; ++r) {
    float linv = 1.0f / o_l[r];
    const int row = q0 + kg * 4 + r;
#pragma unroll
    for (int nb = 0; nb < 4; ++nb) {
      float v = o_acc[nb][r] * linv;
      ao[((size_t)b * S_ + row) * EMBED + h * HDIM + nb * 16 + rl] = f2bf(v);
    }
  }
}

// ---------------------------------------------------------------------------
extern "C" void kernel_launch(void* const* d_in, const int* in_sizes, int n_in,
                              void* d_out, int out_size, void* d_ws, size_t ws_size,
                              hipStream_t stream) {
  const float* x    = (const float*)d_in[0];
  const int*   mask = (const int*)d_in[1];
  const float* Wq   = (const float*)d_in[2];
  const float* bq   = (const float*)d_in[3];
  const float* Wk   = (const float*)d_in[4];
  const float* bk   = (const float*)d_in[5];
  const float* Wv   = (const float*)d_in[6];
  const float* bv   = (const float*)d_in[7];
  const float* Wo   = (const float*)d_in[8];
  const float* bo   = (const float*)d_in[9];

  char* ws = (char*)d_ws;
  ushort_t* xb  = (ushort_t*)(ws);
  ushort_t* wqb = (ushort_t*)(ws + 8388608);
  ushort_t* wkb = (ushort_t*)(ws + 10485760);
  ushort_t* wvb = (ushort_t*)(ws + 12582912);
  ushort_t* wob = (ushort_t*)(ws + 14680064);
  ushort_t* qb  = (ushort_t*)(ws + 16777216);
  ushort_t* kb  = (ushort_t*)(ws + 25165824);
  ushort_t* vtb = (ushort_t*)(ws + 33554432);
  ushort_t* aob = (ushort_t*)(ws + 41943040);

  hipLaunchKernelGGL(convert_kernel, dim3(8192), dim3(256), 0, stream,
                     x, Wq, Wk, Wv, Wo, xb, wqb, wkb, wvb, wob);
  hipLaunchKernelGGL(qkv_kernel, dim3(768), dim3(256), 0, stream,
                     xb, wqb, wkb, wvb, bq, bk, bv, mask, qb, kb, vtb);
  hipLaunchKernelGGL(attn_kernel, dim3(512), dim3(512), 0, stream,
                     qb, kb, vtb, aob);
  hipLaunchKernelGGL(gemm_o_kernel, dim3(32, 8), dim3(256), 0, stream,
                     aob, wob, bo, (float*)d_out);
}

// Round 23
// 111.519 us; speedup vs baseline: 1.6693x; 1.0328x over previous
//
#include <hip/hip_runtime.h>

#define DEV __device__ __forceinline__

typedef __bf16 bf16x8 __attribute__((ext_vector_type(8)));
typedef __bf16 bf16x4 __attribute__((ext_vector_type(4)));
typedef float f32x4 __attribute__((ext_vector_type(4)));
typedef unsigned u32x4 __attribute__((ext_vector_type(4)));
typedef unsigned short ushort_t;

static constexpr int EMBED = 1024;
static constexpr int NHEAD = 16;
static constexpr int HDIM  = 64;
static constexpr int S_    = 2048;
static constexpr float SCALE_L2E = 0.125f * 1.44269504088896340736f; // (1/sqrt(64))*log2(e)

DEV ushort_t f2bf(float f) {
  unsigned u = __builtin_bit_cast(unsigned, f);
  unsigned r = (u + 0x7fffu + ((u >> 16) & 1u)) >> 16;
  return (ushort_t)r;
}

// async global->LDS, 16B per lane; LDS dest is wave-uniform base + lane*16
#define GLOAD_LDS16(g, l)                                                   \
  __builtin_amdgcn_global_load_lds(                                         \
      (const __attribute__((address_space(1))) unsigned int*)(g),           \
      (__attribute__((address_space(3))) unsigned int*)(l), 16, 0, 0)

// explicit drain of global_load_lds before a publish barrier
#define DRAIN_VM() asm volatile("s_waitcnt vmcnt(0)" ::: "memory")

// ---------------------------------------------------------------------------
// fp32 -> bf16 conversion of x and the four weight matrices
// ---------------------------------------------------------------------------
__global__ __launch_bounds__(256) void convert_kernel(
    const float* __restrict__ x,
    const float* __restrict__ wq, const float* __restrict__ wk,
    const float* __restrict__ wv, const float* __restrict__ wo,
    ushort_t* __restrict__ xb, ushort_t* __restrict__ wqb,
    ushort_t* __restrict__ wkb, ushort_t* __restrict__ wvb,
    ushort_t* __restrict__ wob) {
  size_t i = ((size_t)blockIdx.x * blockDim.x + threadIdx.x) * 4;
  const float* src; ushort_t* dst; size_t off;
  if (i < 4194304u)      { src = x;  dst = xb;  off = i; }
  else if (i < 5242880u) { src = wq; dst = wqb; off = i - 4194304u; }
  else if (i < 6291456u) { src = wk; dst = wkb; off = i - 5242880u; }
  else if (i < 7340032u) { src = wv; dst = wvb; off = i - 6291456u; }
  else                   { src = wo; dst = wob; off = i - 7340032u; }
  float4 v = *(const float4*)(src + off);
  ushort4 o;
  o.x = f2bf(v.x); o.y = f2bf(v.y); o.z = f2bf(v.z); o.w = f2bf(v.w);
  *(ushort4*)(dst + off) = o;
}

// ---------------------------------------------------------------------------
// Merged QKV GEMM, 1-D grid of 768 blocks (R12-green single-buffer m97):
//   bid <256 : Q = xb @ Wq^T  -> [B,H,S,D], (acc+bias)*mask*SCALE_L2E
//   bid <512 : K = xb @ Wk^T  -> [B,H,S,D], (acc+bias)*mask
//   else     : V^T (A=Wv, B=xb) -> [B,H,D,S], acc+bias
// ---------------------------------------------------------------------------
__global__ __launch_bounds__(256) void qkv_kernel(
    const ushort_t* __restrict__ xb, const ushort_t* __restrict__ wqb,
    const ushort_t* __restrict__ wkb, const ushort_t* __restrict__ wvb,
    const float* __restrict__ bq, const float* __restrict__ bk,
    const float* __restrict__ bv, const int* __restrict__ mask,
    ushort_t* __restrict__ qo, ushort_t* __restrict__ ko,
    ushort_t* __restrict__ vto) {
  __shared__ __align__(16) unsigned char ldsA[16384];
  __shared__ __align__(16) unsigned char ldsB[16384];
  __shared__ float maskf[2][128];

  const int bid  = blockIdx.x;
  const int tid  = threadIdx.x;
  const int lane = tid & 63;
  const int w    = tid >> 6;
  const int wm   = (w >> 1) * 64;
  const int wn   = (w & 1) * 64;
  const int rl   = lane & 15;
  const int kg   = lane >> 4;

  int mode, ar0, br0;
  const ushort_t *A, *Bm;
  const float* bias;
  if (bid < 512) {
    mode = bid >> 8;                 // 0=Q, 1=K
    int t = bid & 255;
    ar0 = (t & 31) * 128;            // x rows
    br0 = (t >> 5) * 128;            // weight rows
    A = xb; Bm = mode ? wkb : wqb; bias = mode ? bk : bq;
  } else {
    mode = 2;
    int t = bid - 512;
    ar0 = (t & 7) * 128;             // weight rows
    br0 = (t >> 3) * 128;            // x rows
    A = wvb; Bm = xb; bias = bv;
  }

  if (mode < 2) {
    int hl = tid >> 7, sl = tid & 127;
    int m = ar0 + sl;
    int b = m >> 11, s = m & 2047;
    int h = (br0 >> 6) + hl;
    maskf[hl][sl] = (float)mask[((size_t)b * NHEAD + h) * S_ + s];
  }

  f32x4 acc[4][4];
#pragma unroll
  for (int i = 0; i < 4; ++i)
#pragma unroll
    for (int j = 0; j < 4; ++j) acc[i][j] = f32x4{0.f, 0.f, 0.f, 0.f};

  auto STAGE = [&](int kt) {
    const int k0 = kt * 64;
#pragma unroll
    for (int s = 0; s < 8; ++s) {
      const int basev = s * 256 + w * 64;   // wave-uniform
      const int Lb = basev & 1023;
      const int L = Lb + lane;
      const int row = L >> 3;
      const int gu = (L & 7) ^ (row & 7);
      if (s < 4) {
        GLOAD_LDS16(A + (size_t)(ar0 + row) * EMBED + k0 + gu * 8, &ldsA[Lb * 16]);
      } else {
        GLOAD_LDS16(Bm + (size_t)(br0 + row) * EMBED + k0 + gu * 8, &ldsB[Lb * 16]);
      }
    }
  };

  for (int kt = 0; kt < 16; ++kt) {
    if (kt) __syncthreads();          // all waves done reading previous tile
    STAGE(kt);
    DRAIN_VM();                       // my loads landed
    __syncthreads();                  // everyone's loads landed
#pragma unroll
    for (int kk = 0; kk < 2; ++kk) {
      bf16x8 af[4], bfr[4];
#pragma unroll
      for (int mb = 0; mb < 4; ++mb) {
        const int row = wm + mb * 16 + rl;
        const int off = (kk * 64 + kg * 16) ^ ((row & 7) << 4);
        af[mb] = *(const bf16x8*)(ldsA + row * 128 + off);
      }
#pragma unroll
      for (int nb = 0; nb < 4; ++nb) {
        const int row = wn + nb * 16 + rl;
        const int off = (kk * 64 + kg * 16) ^ ((row & 7) << 4);
        bfr[nb] = *(const bf16x8*)(ldsB + row * 128 + off);
      }
#pragma unroll
      for (int mb = 0; mb < 4; ++mb)
#pragma unroll
        for (int nb = 0; nb < 4; ++nb)
          acc[mb][nb] = __builtin_amdgcn_mfma_f32_16x16x32_bf16(
              af[mb], bfr[nb], acc[mb][nb], 0, 0, 0);
    }
  }

  // epilogue — D layout: row(A idx)=(lane>>4)*4+r, col(B idx)=lane&15
#pragma unroll
  for (int mb = 0; mb < 4; ++mb)
#pragma unroll
    for (int nb = 0; nb < 4; ++nb)
#pragma unroll
      for (int r = 0; r < 4; ++r) {
        int row_l = wm + mb * 16 + kg * 4 + r;
        int col_l = wn + nb * 16 + rl;
        float v = acc[mb][nb][r];
        if (mode < 2) {
          int m = ar0 + row_l, n = br0 + col_l;
          v = (v + bias[n]) * maskf[col_l >> 6][row_l];
          if (mode == 0) v *= SCALE_L2E;
          int b = m >> 11, s = m & 2047, h = n >> 6, d = n & 63;
          ushort_t* o = mode ? ko : qo;
          o[(((size_t)(b * NHEAD + h)) * S_ + s) * HDIM + d] = f2bf(v);
        } else {
          int n = ar0 + row_l, m = br0 + col_l;
          v += bias[n];
          int b = m >> 11, s = m & 2047, h = n >> 6, d = n & 63;
          vto[(((size_t)(b * NHEAD + h)) * HDIM + d) * S_ + s] = f2bf(v);
        }
      }
}

// ---------------------------------------------------------------------------
// O projection GEMM: out[m][n] = aob[m][:] . Wo[n][:] + bo[n]  (fp32 out)
// R12-green single-buffer m97 structure.
// ---------------------------------------------------------------------------
__global__ __launch_bounds__(256) void gemm_o_kernel(
    const ushort_t* __restrict__ A, const ushort_t* __restrict__ Bm,
    const float* __restrict__ bias, float* __restrict__ outp) {
  __shared__ __align__(16) unsigned char ldsA[16384];
  __shared__ __align__(16) unsigned char ldsB[16384];

  const int tid  = threadIdx.x;
  const int lane = tid & 63;
  const int w    = tid >> 6;
  const int ar0  = blockIdx.x * 128;
  const int br0  = blockIdx.y * 128;
  const int wm   = (w >> 1) * 64;
  const int wn   = (w & 1) * 64;
  const int rl   = lane & 15;
  const int kg   = lane >> 4;

  f32x4 acc[4][4];
#pragma unroll
  for (int i = 0; i < 4; ++i)
#pragma unroll
    for (int j = 0; j < 4; ++j) acc[i][j] = f32x4{0.f, 0.f, 0.f, 0.f};

  auto STAGE = [&](int kt) {
    const int k0 = kt * 64;
#pragma unroll
    for (int s = 0; s < 8; ++s) {
      const int basev = s * 256 + w * 64;
      const int Lb = basev & 1023;
      const int L = Lb + lane;
      const int row = L >> 3;
      const int gu = (L & 7) ^ (row & 7);
      if (s < 4) {
        GLOAD_LDS16(A + (size_t)(ar0 + row) * EMBED + k0 + gu * 8, &ldsA[Lb * 16]);
      } else {
        GLOAD_LDS16(Bm + (size_t)(br0 + row) * EMBED + k0 + gu * 8, &ldsB[Lb * 16]);
      }
    }
  };

  for (int kt = 0; kt < 16; ++kt) {
    if (kt) __syncthreads();
    STAGE(kt);
    DRAIN_VM();
    __syncthreads();
#pragma unroll
    for (int kk = 0; kk < 2; ++kk) {
      bf16x8 af[4], bfr[4];
#pragma unroll
      for (int mb = 0; mb < 4; ++mb) {
        const int row = wm + mb * 16 + rl;
        const int off = (kk * 64 + kg * 16) ^ ((row & 7) << 4);
        af[mb] = *(const bf16x8*)(ldsA + row * 128 + off);
      }
#pragma unroll
      for (int nb = 0; nb < 4; ++nb) {
        const int row = wn + nb * 16 + rl;
        const int off = (kk * 64 + kg * 16) ^ ((row & 7) << 4);
        bfr[nb] = *(const bf16x8*)(ldsB + row * 128 + off);
      }
#pragma unroll
      for (int mb = 0; mb < 4; ++mb)
#pragma unroll
        for (int nb = 0; nb < 4; ++nb)
          acc[mb][nb] = __builtin_amdgcn_mfma_f32_16x16x32_bf16(
              af[mb], bfr[nb], acc[mb][nb], 0, 0, 0);
    }
  }

#pragma unroll
  for (int mb = 0; mb < 4; ++mb)
#pragma unroll
    for (int nb = 0; nb < 4; ++nb)
#pragma unroll
      for (int r = 0; r < 4; ++r) {
        int m = ar0 + wm + mb * 16 + kg * 4 + r;
        int n = br0 + wn + nb * 16 + rl;
        outp[(size_t)m * EMBED + n] = acc[mb][nb][r] + bias[n];
      }
}

// ---------------------------------------------------------------------------
// Flash attention, swapped-QK^T, fixed-exponent softmax — 2-TILE UNROLL
// (intra-wave ILP): per iteration process tiles A=kt, B=kt+1:
//   QK_A; QK_B; SM_A-writes | fence | {P_A read, l_A, PV_A  ||  SM_B VALU}
//   | fence | P_B read, l_B, PV_B
// so PV_A MFMAs co-issue with SM_B exp2 (separate pipes, same wave).
// 4 KV slots (tile kt -> slot kt&3), 2-tiles-ahead prefetch, counted
// vmcnt(4) with a full iteration of slack; raw s_barrier (2 per 2 tiles).
// P buffer reused A->B per wave (may-alias ordering + in-order DS).
// 8 waves x 16 q; XCD-resident decode; s_setprio around MFMA clusters.
// LDS: K 4x8KB + V 4x8KB + P 8x2KB = 80KB -> 2 blocks/CU.
// ---------------------------------------------------------------------------
__global__ __launch_bounds__(512) void attn_kernel(
    const ushort_t* __restrict__ qp, const ushort_t* __restrict__ kp,
    const ushort_t* __restrict__ vtp, ushort_t* __restrict__ ao) {
  __shared__ __align__(16) unsigned char ldsK[4][8192];
  __shared__ __align__(16) unsigned char ldsV[4][8192];
  __shared__ __align__(16) unsigned char ldsP[8][2048];

  const int bid  = blockIdx.x;
  const int bh   = (bid & 7) * 4 + (bid >> 7); // XCD-resident head slice
  const int qt   = (bid >> 3) & 15;
  const int tid  = threadIdx.x;
  const int lane = tid & 63;
  const int w    = tid >> 6;                  // 0..7
  const int q0   = qt * 128 + w * 16;         // wave's q base (16 rows)
  const int rl   = lane & 15;
  const int kg   = lane >> 4;
  const int pswz = (rl & 7) << 4;

  const bf16x8 ones = __builtin_bit_cast(bf16x8,
      u32x4{0x3F803F80u, 0x3F803F80u, 0x3F803F80u, 0x3F803F80u});

  // Q fragments (B-operand): lane (rl,kg) holds Q[q=rl][d=kk*32+kg*8..+8]
  bf16x8 qa[2];
#pragma unroll
  for (int kk = 0; kk < 2; ++kk)
    qa[kk] = *(const bf16x8*)(qp + ((size_t)bh * S_ + q0 + rl) * HDIM +
                              kk * 32 + kg * 8);

  f32x4 o_acc[4];
  f32x4 o_l = f32x4{0.f, 0.f, 0.f, 0.f};
#pragma unroll
  for (int nb = 0; nb < 4; ++nb) o_acc[nb] = f32x4{0.f, 0.f, 0.f, 0.f};

  unsigned char* pb = ldsP[w];

  // stage KV tile kt into slot: 512 K units + 512 V units, 2 insts/thread
  auto STAGE = [&](int kt, int slot) {
#pragma unroll
    for (int s = 0; s < 2; ++s) {
      const int Lb = w * 64;                  // wave-uniform, 8 waves x 64
      const int L = Lb + lane;
      const int row = L >> 3;
      const int gu = (L & 7) ^ (row & 7);
      if (s == 0) {
        GLOAD_LDS16(kp + ((size_t)bh * S_ + (size_t)kt * 64 + row) * HDIM + gu * 8,
                    &ldsK[slot][L * 16]);
      } else {
        GLOAD_LDS16(vtp + ((size_t)bh * HDIM + row) * S_ + (size_t)kt * 64 + gu * 8,
                    &ldsV[slot][L * 16]);
      }
    }
  };

  // per-tile pieces (static indexing; called twice per iteration)
  auto QK = [&](int slot, f32x4 sa[4]) {
#pragma unroll
    for (int nb = 0; nb < 4; ++nb) {
      const int row = nb * 16 + rl;
#pragma unroll
      for (int kk = 0; kk < 2; ++kk) {
        bf16x8 kf = *(const bf16x8*)(ldsK[slot] + row * 128 +
                                     ((kk * 64 + kg * 16) ^ ((row & 7) << 4)));
        sa[nb] = __builtin_amdgcn_mfma_f32_16x16x32_bf16(kf, qa[kk], sa[nb], 0, 0, 0);
      }
    }
  };
  auto SMW = [&](const f32x4 sa[4]) {          // exp2 -> bf16 -> P writes
#pragma unroll
    for (int nb = 0; nb < 4; ++nb) {
      bf16x4 pk4;
#pragma unroll
      for (int r = 0; r < 4; ++r)
        pk4[r] = (__bf16)__builtin_amdgcn_exp2f(sa[nb][r]);
      *(bf16x4*)(pb + rl * 128 + ((nb * 32 + kg * 8) ^ pswz)) = pk4;
    }
  };
  auto PVL = [&](int slot) {                   // P read, l, PV
    bf16x8 pa[2];
#pragma unroll
    for (int kk = 0; kk < 2; ++kk)
      pa[kk] = *(const bf16x8*)(pb + rl * 128 + ((kk * 64 + kg * 16) ^ pswz));
    o_l = __builtin_amdgcn_mfma_f32_16x16x32_bf16(pa[0], ones, o_l, 0, 0, 0);
    o_l = __builtin_amdgcn_mfma_f32_16x16x32_bf16(pa[1], ones, o_l, 0, 0, 0);
#pragma unroll
    for (int nb = 0; nb < 4; ++nb) {
      const int row = nb * 16 + rl;
#pragma unroll
      for (int kk = 0; kk < 2; ++kk) {
        bf16x8 vb = *(const bf16x8*)(ldsV[slot] + row * 128 +
                                     ((kk * 64 + kg * 16) ^ ((row & 7) << 4)));
        o_acc[nb] = __builtin_amdgcn_mfma_f32_16x16x32_bf16(pa[kk], vb, o_acc[nb], 0, 0, 0);
      }
    }
  };

  STAGE(0, 0); STAGE(1, 1); STAGE(2, 2); STAGE(3, 3);
  asm volatile("s_waitcnt vmcnt(4) lgkmcnt(0)" ::: "memory"); // tiles 0,1 landed
  __builtin_amdgcn_s_barrier();

  for (int kt = 0; kt < 32; kt += 2) {
    const int s0 = kt & 3, s1 = (kt + 1) & 3;

    f32x4 saA[4], saB[4];
#pragma unroll
    for (int nb = 0; nb < 4; ++nb) { saA[nb] = f32x4{0.f,0.f,0.f,0.f}; saB[nb] = f32x4{0.f,0.f,0.f,0.f}; }

    __builtin_amdgcn_s_setprio(1);
    QK(s0, saA);
    QK(s1, saB);
    __builtin_amdgcn_s_setprio(0);

    SMW(saA);
    asm volatile("s_waitcnt lgkmcnt(0)" ::: "memory");
    __builtin_amdgcn_sched_barrier(0);

    // region: PV_A MFMAs interleave with SM_B VALU (independent, same wave)
    __builtin_amdgcn_s_setprio(1);
    PVL(s0);
    __builtin_amdgcn_s_setprio(0);
    SMW(saB);
    asm volatile("s_waitcnt lgkmcnt(0)" ::: "memory");
    __builtin_amdgcn_sched_barrier(0);

    __builtin_amdgcn_s_setprio(1);
    PVL(s1);
    __builtin_amdgcn_s_setprio(0);

    // publish: all waves done reading slots s0,s1; restage them 2 ahead
    __builtin_amdgcn_s_barrier();
    if (kt + 4 < 32) {
      STAGE(kt + 4, s0); STAGE(kt + 5, s1);
      asm volatile("s_waitcnt vmcnt(4) lgkmcnt(0)" ::: "memory"); // kt+2,kt+3 landed
    } else {
      asm volatile("s_waitcnt vmcnt(0) lgkmcnt(0)" ::: "memory");
    }
    __builtin_amdgcn_s_barrier();
  }

  // epilogue: O[q=kg*4+r][d=nb*16+rl] / l[q]; o_l aligned with o_acc
  const int b = bh >> 4, h = bh & 15;
#pragma unroll
  for (int r = 0; r < 4; ++r) {
    float linv = 1.0f / o_l[r];
    const int row = q0 + kg * 4 + r;
#pragma unroll
    for (int nb = 0; nb < 4; ++nb) {
      float v = o_acc[nb][r] * linv;
      ao[((size_t)b * S_ + row) * EMBED + h * HDIM + nb * 16 + rl] = f2bf(v);
    }
  }
}

// ---------------------------------------------------------------------------
extern "C" void kernel_launch(void* const* d_in, const int* in_sizes, int n_in,
                              void* d_out, int out_size, void* d_ws, size_t ws_size,
                              hipStream_t stream) {
  const float* x    = (const float*)d_in[0];
  const int*   mask = (const int*)d_in[1];
  const float* Wq   = (const float*)d_in[2];
  const float* bq   = (const float*)d_in[3];
  const float* Wk   = (const float*)d_in[4];
  const float* bk   = (const float*)d_in[5];
  const float* Wv   = (const float*)d_in[6];
  const float* bv   = (const float*)d_in[7];
  const float* Wo   = (const float*)d_in[8];
  const float* bo   = (const float*)d_in[9];

  char* ws = (char*)d_ws;
  ushort_t* xb  = (ushort_t*)(ws);
  ushort_t* wqb = (ushort_t*)(ws + 8388608);
  ushort_t* wkb = (ushort_t*)(ws + 10485760);
  ushort_t* wvb = (ushort_t*)(ws + 12582912);
  ushort_t* wob = (ushort_t*)(ws + 14680064);
  ushort_t* qb  = (ushort_t*)(ws + 16777216);
  ushort_t* kb  = (ushort_t*)(ws + 25165824);
  ushort_t* vtb = (ushort_t*)(ws + 33554432);
  ushort_t* aob = (ushort_t*)(ws + 41943040);

  hipLaunchKernelGGL(convert_kernel, dim3(8192), dim3(256), 0, stream,
                     x, Wq, Wk, Wv, Wo, xb, wqb, wkb, wvb, wob);
  hipLaunchKernelGGL(qkv_kernel, dim3(768), dim3(256), 0, stream,
                     xb, wqb, wkb, wvb, bq, bk, bv, mask, qb, kb, vtb);
  hipLaunchKernelGGL(attn_kernel, dim3(512), dim3(512), 0, stream,
                     qb, kb, vtb, aob);
  hipLaunchKernelGGL(gemm_o_kernel, dim3(32, 8), dim3(256), 0, stream,
                     aob, wob, bo, (float*)d_out);
}